// Round 3
// baseline (883.599 us; speedup 1.0000x reference)
//
#include <hip/hip_runtime.h>
#include <math.h>

#define ED 300
#define Hh 60
#define G4 240
#define NRELc 5
#define Bc 1024
#define Pc 16
#define Lc 8
#define Nc (Bc*Pc)        /* 16384 sequences */
#define Rc (Nc*Lc)        /* 131072 rows, r = t*Nc + n */

typedef __attribute__((ext_vector_type(8))) short short8v;   // 8 bf16 (4 VGPRs)
typedef __attribute__((ext_vector_type(4))) short short4v;
typedef __attribute__((ext_vector_type(4))) unsigned short ushort4v;
typedef __attribute__((ext_vector_type(4))) float f32x4;
typedef unsigned short u16;

__device__ __forceinline__ float sigf(float x){ return 1.f/(1.f+__expf(-x)); }
__device__ __forceinline__ float tanhfast(float x){
    x = fminf(fmaxf(x,-15.f),15.f);
    float e = __expf(-2.f*x);
    return (1.f-e)/(1.f+e);
}
__device__ __forceinline__ u16 f2b(float f){        // fp32 -> bf16 bits, RNE
    union{float f; unsigned u;} v; v.f=f;
    unsigned r = v.u + 0x7fffu + ((v.u>>16)&1u);
    return (u16)(r>>16);
}
__device__ __forceinline__ float b2f(u16 b){ return __uint_as_float(((unsigned)b)<<16); }

// Build fragment-order (pre-swizzled) bf16 weights + (k,240) fp32 recurrent weights.
// Frag layout per lane l, elem e: j = m*16+(l&15); k = ks*32 + 16*(e>>2) + 4*(l>>4) + (e&3).
// k==K real dim holds folded bias (feature value 1.0 supplied on the B side).
__global__ __launch_bounds__(256) void prep_kernel(
    const float* __restrict__ Wih0, const float* __restrict__ Whh0,
    const float* __restrict__ Wih1, const float* __restrict__ Whh1,
    const float* __restrict__ bih0, const float* __restrict__ bhh0,
    const float* __restrict__ bih1, const float* __restrict__ bhh1,
    u16* __restrict__ Aswz0, u16* __restrict__ Aswz1,
    float* __restrict__ WhhT0, float* __restrict__ WhhT1)
{
    const int i0 = blockIdx.x*256 + threadIdx.x;
    const int stride = gridDim.x*256;
    for (int idx=i0; idx<15*10*64*8; idx+=stride){
        int e = idx&7, l = (idx>>3)&63, mk = idx>>9;
        int m = mk/10, ks = mk - m*10;
        int j = m*16 + (l&15);
        int k = ks*32 + ((e>>2)<<4) + ((l>>4)<<2) + (e&3);
        float v = 0.f;
        if (k < 310)      v = Wih0[j*310 + k];
        else if (k==310)  v = bih0[j] + bhh0[j];
        Aswz0[idx] = f2b(v);
    }
    for (int idx=i0; idx<15*2*64*8; idx+=stride){
        int e = idx&7, l = (idx>>3)&63, mk = idx>>9;
        int m = mk>>1, ks = mk&1;
        int j = m*16 + (l&15);
        int k = ks*32 + ((e>>2)<<4) + ((l>>4)<<2) + (e&3);
        float v = 0.f;
        if (k < 60)       v = Wih1[j*60 + k];
        else if (k==60)   v = bih1[j] + bhh1[j];
        Aswz1[idx] = f2b(v);
    }
    for (int idx=i0; idx<60*240; idx+=stride){
        int k = idx/240, j = idx - k*240;
        WhhT0[idx] = Whh0[j*60 + k];
        WhhT1[idx] = Whh1[j*60 + k];
    }
}

// gin0 = [bias|Wih0] @ feats^T via MFMA. Block: 128 rows(N) x 240(M), 4 waves, wave = 2 N-tiles.
__global__ __launch_bounds__(256,2) void gin0_kernel(
    const int* __restrict__ widx, const int* __restrict__ pidx,
    const int* __restrict__ didx, const int* __restrict__ ridx,
    const float* __restrict__ wemb, const float* __restrict__ pemb,
    const float* __restrict__ demb, const float* __restrict__ remb,
    const u16* __restrict__ Aswz, u16* __restrict__ gout)
{
    __shared__ u16 feats[128*320];          // 80KB, XOR-swizzled row-major bf16
    __shared__ int lw[128], lp[128], ld[128], lr[128];
    const int tid = threadIdx.x;
    const int r0 = blockIdx.x*128;

    if (tid < 128){
        int r = r0 + tid;
        int t = r >> 14, n = r & (Nc-1);
        lw[tid] = widx[n*Lc+t];
        lp[tid] = pidx[n*Lc+t];
        ld[tid] = didx[n*Lc+t];
        lr[tid] = ridx[n*Lc+t];
    }
    __syncthreads();

    // Gather: 128 rows x 80 chunks of 4 (k = 4c..4c+3). k=310 -> 1.0 (bias slot).
    for (int it=0; it<40; ++it){
        int idx = it*256 + tid;
        int row = idx/80, c = idx - row*80;
        float x0=0.f,x1=0.f,x2=0.f,x3=0.f;
        if (c < 75){
            const float4 v = ((const float4*)(wemb + (size_t)lw[row]*300))[c];
            x0=v.x; x1=v.y; x2=v.z; x3=v.w;
        } else if (c==75){
            const float* p = pemb + lp[row]*4;
            x0=p[0]; x1=p[1]; x2=p[2]; x3=p[3];
        } else if (c==76){
            const float* p = demb + ld[row]*5;
            x0=p[0]; x1=p[1]; x2=p[2]; x3=p[3];
        } else if (c==77){
            x0=demb[ld[row]*5+4]; x1=remb[lr[row]]; x2=1.f; x3=0.f;
        }
        ushort4v w; w[0]=f2b(x0); w[1]=f2b(x1); w[2]=f2b(x2); w[3]=f2b(x3);
        int byteoff = (row*640 + c*8) ^ ((row&7)<<4);
        *(ushort4v*)((char*)feats + byteoff) = w;
    }
    __syncthreads();

    const int l  = tid & 63;
    const int wv = __builtin_amdgcn_readfirstlane(tid>>6);
    f32x4 acc[15][2];
#pragma unroll
    for (int m=0;m<15;m++){
        acc[m][0] = f32x4{0.f,0.f,0.f,0.f};
        acc[m][1] = f32x4{0.f,0.f,0.f,0.f};
    }
    const int row0 = wv*32 + (l&15);
    const int row1 = row0 + 16;
    const int swz  = (row0&7)<<4;           // row1 has same (row&7)

    for (int ks=0; ks<10; ++ks){
        int b0 = row0*640 + ks*64 + ((l>>4)<<3);
        int b1 = row1*640 + ks*64 + ((l>>4)<<3);
        short4v lo0 = *(const short4v*)((char*)feats + ( b0      ^ swz));
        short4v hi0 = *(const short4v*)((char*)feats + ((b0+32) ^ swz));
        short4v lo1 = *(const short4v*)((char*)feats + ( b1      ^ swz));
        short4v hi1 = *(const short4v*)((char*)feats + ((b1+32) ^ swz));
        short8v bf0 = {lo0[0],lo0[1],lo0[2],lo0[3],hi0[0],hi0[1],hi0[2],hi0[3]};
        short8v bf1 = {lo1[0],lo1[1],lo1[2],lo1[3],hi1[0],hi1[1],hi1[2],hi1[3]};
#pragma unroll
        for (int m=0;m<15;m++){
            short8v a = *(const short8v*)(Aswz + (size_t)(((m*10+ks)<<6) + l)*8);
            acc[m][0] = __builtin_amdgcn_mfma_f32_16x16x32_bf16(a, bf0, acc[m][0], 0,0,0);
            acc[m][1] = __builtin_amdgcn_mfma_f32_16x16x32_bf16(a, bf1, acc[m][1], 0,0,0);
        }
    }
    const int rA = r0 + row0;
#pragma unroll
    for (int m=0;m<15;m++){
#pragma unroll
        for (int i=0;i<4;i++){
            int j = m*16 + ((l>>4)<<2) + i;
            gout[(size_t)j*Rc + rA]      = f2b(acc[m][0][i]);
            gout[(size_t)j*Rc + rA + 16] = f2b(acc[m][1][i]);
        }
    }
}

// gin1 = [bias|Wih1] @ h1^T via MFMA. h1R rows: 64 bf16 (60 h, 1.0, 0,0,0).
__global__ __launch_bounds__(256,2) void gin1_kernel(
    const u16* __restrict__ h1R, const u16* __restrict__ Aswz, u16* __restrict__ gout)
{
    __shared__ u16 feats[128*64];           // 16KB
    const int tid = threadIdx.x;
    const int r0 = blockIdx.x*128;

    for (int it=0; it<8; ++it){
        int idx = it*256 + tid;
        int row = idx>>4, c = idx&15;
        ushort4v v = *(const ushort4v*)(h1R + ((size_t)(r0+row)<<6) + (c<<2));
        int byteoff = (row*128 + c*8) ^ ((row&7)<<4);
        *(ushort4v*)((char*)feats + byteoff) = v;
    }
    __syncthreads();

    const int l  = tid & 63;
    const int wv = __builtin_amdgcn_readfirstlane(tid>>6);
    f32x4 acc[15][2];
#pragma unroll
    for (int m=0;m<15;m++){
        acc[m][0] = f32x4{0.f,0.f,0.f,0.f};
        acc[m][1] = f32x4{0.f,0.f,0.f,0.f};
    }
    const int row0 = wv*32 + (l&15);
    const int row1 = row0 + 16;
    const int swz  = (row0&7)<<4;

#pragma unroll
    for (int ks=0; ks<2; ++ks){
        int b0 = row0*128 + ks*64 + ((l>>4)<<3);
        int b1 = row1*128 + ks*64 + ((l>>4)<<3);
        short4v lo0 = *(const short4v*)((char*)feats + ( b0      ^ swz));
        short4v hi0 = *(const short4v*)((char*)feats + ((b0+32) ^ swz));
        short4v lo1 = *(const short4v*)((char*)feats + ( b1      ^ swz));
        short4v hi1 = *(const short4v*)((char*)feats + ((b1+32) ^ swz));
        short8v bf0 = {lo0[0],lo0[1],lo0[2],lo0[3],hi0[0],hi0[1],hi0[2],hi0[3]};
        short8v bf1 = {lo1[0],lo1[1],lo1[2],lo1[3],hi1[0],hi1[1],hi1[2],hi1[3]};
#pragma unroll
        for (int m=0;m<15;m++){
            short8v a = *(const short8v*)(Aswz + (size_t)((((m<<1)+ks)<<6) + l)*8);
            acc[m][0] = __builtin_amdgcn_mfma_f32_16x16x32_bf16(a, bf0, acc[m][0], 0,0,0);
            acc[m][1] = __builtin_amdgcn_mfma_f32_16x16x32_bf16(a, bf1, acc[m][1], 0,0,0);
        }
    }
    const int rA = r0 + row0;
#pragma unroll
    for (int m=0;m<15;m++){
#pragma unroll
        for (int i=0;i<4;i++){
            int j = m*16 + ((l>>4)<<2) + i;
            gout[(size_t)j*Rc + rA]      = f2b(acc[m][0][i]);
            gout[(size_t)j*Rc + rA + 16] = f2b(acc[m][1][i]);
        }
    }
}

// Layer-0 recurrence. 512 thr = 8 waves: wave (g=wv>>1, half=wv&1) owns 30 gate rows.
__global__ __launch_bounds__(512,2) void rec0_kernel(
    const u16* __restrict__ gin, const float* __restrict__ WhhT, u16* __restrict__ h1R)
{
    __shared__ float hlds[64][60];
    __shared__ float gact[4][60][64];
    const int tid = threadIdx.x;
    const int l   = tid & 63;
    const int wv  = __builtin_amdgcn_readfirstlane(tid>>6);
    const int g = wv>>1, hf = wv&1;
    const int n0 = blockIdx.x*64;

    for (int idx=tid; idx<64*60; idx+=512) ((float*)hlds)[idx]=0.f;
    float c_reg[8];
#pragma unroll
    for (int i=0;i<8;i++) c_reg[i]=0.f;
    __syncthreads();

    const u16*  gb0 = gin + (size_t)(g*60+hf*30)*Rc + n0 + l;
    const float* wb = WhhT + g*60 + hf*30;

    for (int t=0;t<Lc;t++){
        float acc[30];
        const u16* gb = gb0 + (size_t)t*Nc;
#pragma unroll
        for (int i=0;i<30;i++) acc[i] = b2f(gb[(size_t)i*Rc]);
#pragma unroll
        for (int k4=0;k4<15;k4++){
            float4 h4 = *(const float4*)&hlds[l][k4*4];
            const float* w0 = wb + (k4*4+0)*G4;
            const float* w1 = wb + (k4*4+1)*G4;
            const float* w2 = wb + (k4*4+2)*G4;
            const float* w3 = wb + (k4*4+3)*G4;
#pragma unroll
            for (int i=0;i<30;i++) acc[i] += w0[i]*h4.x + w1[i]*h4.y + w2[i]*h4.z + w3[i]*h4.w;
        }
        if (g==2){
#pragma unroll
            for (int i=0;i<30;i++) gact[2][hf*30+i][l] = tanhfast(acc[i]);
        } else {
#pragma unroll
            for (int i=0;i<30;i++) gact[g][hf*30+i][l] = sigf(acc[i]);
        }
        __syncthreads();
#pragma unroll
        for (int i=0;i<8;i++){
            int u = wv + 8*i;
            if (u < 60){
                float iv = gact[0][u][l], fv = gact[1][u][l];
                float gv = gact[2][u][l], ov = gact[3][u][l];
                float c = fv*c_reg[i] + iv*gv;
                c_reg[i] = c;
                hlds[l][u] = ov*tanhfast(c);
            }
        }
        __syncthreads();
        // coalesced dump: h1R[r][0..63] = {h[0..59], 1.0, 0,0,0}
#pragma unroll
        for (int it=0; it<8; ++it){
            int nl = it*8 + wv;
            float v = (l<60) ? hlds[nl][l] : ((l==60)?1.f:0.f);
            h1R[((size_t)(t*Nc + n0 + nl)<<6) + l] = f2b(v);
        }
        __syncthreads();
    }
}

// Layer-1 recurrence; captures h2 at t==len-1 into lastT[u][n] (fp32).
__global__ __launch_bounds__(512,2) void rec1_kernel(
    const u16* __restrict__ gin, const float* __restrict__ WhhT,
    const int* __restrict__ lens, float* __restrict__ lastT)
{
    __shared__ float hlds[64][60];
    __shared__ float gact[4][60][64];
    const int tid = threadIdx.x;
    const int l   = tid & 63;
    const int wv  = __builtin_amdgcn_readfirstlane(tid>>6);
    const int g = wv>>1, hf = wv&1;
    const int n0 = blockIdx.x*64;
    const int mylen = lens[n0+l];

    for (int idx=tid; idx<64*60; idx+=512) ((float*)hlds)[idx]=0.f;
    float c_reg[8];
#pragma unroll
    for (int i=0;i<8;i++) c_reg[i]=0.f;
    __syncthreads();

    const u16*  gb0 = gin + (size_t)(g*60+hf*30)*Rc + n0 + l;
    const float* wb = WhhT + g*60 + hf*30;

    for (int t=0;t<Lc;t++){
        float acc[30];
        const u16* gb = gb0 + (size_t)t*Nc;
#pragma unroll
        for (int i=0;i<30;i++) acc[i] = b2f(gb[(size_t)i*Rc]);
#pragma unroll
        for (int k4=0;k4<15;k4++){
            float4 h4 = *(const float4*)&hlds[l][k4*4];
            const float* w0 = wb + (k4*4+0)*G4;
            const float* w1 = wb + (k4*4+1)*G4;
            const float* w2 = wb + (k4*4+2)*G4;
            const float* w3 = wb + (k4*4+3)*G4;
#pragma unroll
            for (int i=0;i<30;i++) acc[i] += w0[i]*h4.x + w1[i]*h4.y + w2[i]*h4.z + w3[i]*h4.w;
        }
        if (g==2){
#pragma unroll
            for (int i=0;i<30;i++) gact[2][hf*30+i][l] = tanhfast(acc[i]);
        } else {
#pragma unroll
            for (int i=0;i<30;i++) gact[g][hf*30+i][l] = sigf(acc[i]);
        }
        __syncthreads();
#pragma unroll
        for (int i=0;i<8;i++){
            int u = wv + 8*i;
            if (u < 60){
                float iv = gact[0][u][l], fv = gact[1][u][l];
                float gv = gact[2][u][l], ov = gact[3][u][l];
                float c = fv*c_reg[i] + iv*gv;
                c_reg[i] = c;
                float h = ov*tanhfast(c);
                hlds[l][u] = h;
                if (t == mylen-1) lastT[(size_t)u*Nc + n0 + l] = h;
            }
        }
        __syncthreads();
    }
}

// Mean over P, concat [xw, path, yw] @ W^T + b, softmax. One block per batch row.
__global__ __launch_bounds__(320) void final_kernel(
    const float* __restrict__ lastT, const float* __restrict__ counts,
    const int* __restrict__ pair, const float* __restrict__ wemb,
    const float* __restrict__ W, const float* __restrict__ bvec,
    float* __restrict__ out)
{
    __shared__ float path[Hh];
    __shared__ float red[NRELc];
    const int b = blockIdx.x;
    const int tid = threadIdx.x;

    if (tid < Hh){
        float s=0.f, cs=0.f;
        for (int p=0;p<Pc;p++){
            float cnt = counts[b*Pc+p];
            s  += lastT[(size_t)tid*Nc + b*Pc+p]*cnt;
            cs += cnt;
        }
        path[tid] = s/cs;
    }
    __syncthreads();

    const int rrel = tid>>6;
    const int lane = tid&63;
    const int xi = pair[b*2+0], yi = pair[b*2+1];
    const float* Wr = W + rrel*(2*ED+Hh);
    float acc=0.f;
    for (int d=lane; d<ED; d+=64) acc += wemb[xi*ED+d]*Wr[d];
    for (int k=lane; k<Hh; k+=64) acc += path[k]*Wr[ED+k];
    for (int d=lane; d<ED; d+=64) acc += wemb[yi*ED+d]*Wr[ED+Hh+d];
    for (int off=32; off>0; off>>=1) acc += __shfl_down(acc, off);
    if (lane==0) red[rrel] = acc + bvec[rrel];
    __syncthreads();

    if (tid==0){
        float m=red[0];
        for (int i=1;i<NRELc;i++) m=fmaxf(m,red[i]);
        float e[NRELc]; float s=0.f;
        for (int i=0;i<NRELc;i++){ e[i]=__expf(red[i]-m); s+=e[i]; }
        float inv=1.f/s;
        for (int i=0;i<NRELc;i++) out[b*NRELc+i]=e[i]*inv;
    }
}

extern "C" void kernel_launch(void* const* d_in, const int* in_sizes, int n_in,
                              void* d_out, int out_size, void* d_ws, size_t ws_size,
                              hipStream_t stream)
{
    const int*   word_idx = (const int*)d_in[0];
    const int*   pos_idx  = (const int*)d_in[1];
    const int*   dep_idx  = (const int*)d_in[2];
    const int*   dir_idx  = (const int*)d_in[3];
    const int*   lengths  = (const int*)d_in[4];
    const float* counts   = (const float*)d_in[5];
    const int*   pair_idx = (const int*)d_in[6];
    const float* word_emb = (const float*)d_in[7];
    const float* pos_emb  = (const float*)d_in[8];
    const float* dep_emb  = (const float*)d_in[9];
    const float* dir_emb  = (const float*)d_in[10];
    const float* Wih0     = (const float*)d_in[11];
    const float* Whh0     = (const float*)d_in[12];
    const float* bih0     = (const float*)d_in[13];
    const float* bhh0     = (const float*)d_in[14];
    const float* Wih1     = (const float*)d_in[15];
    const float* Whh1     = (const float*)d_in[16];
    const float* bih1     = (const float*)d_in[17];
    const float* bhh1     = (const float*)d_in[18];
    const float* W        = (const float*)d_in[19];
    const float* bvec     = (const float*)d_in[20];
    float* out = (float*)d_out;

    // Workspace carve-up (~84 MB). fp32 region first, then bf16 (u16) region.
    float* p = (float*)d_ws;
    float* WhhT0 = p; p += 60*G4;
    float* WhhT1 = p; p += 60*G4;
    float* lastT = p; p += (size_t)Nc*Hh;
    u16* q = (u16*)p;
    u16* Aswz0 = q; q += 15*10*64*8;
    u16* Aswz1 = q; q += 15*2*64*8;
    u16* h1R   = q; q += (size_t)Rc*64;
    u16* ginbuf= q; q += (size_t)G4*Rc;   // shared by gin0 (layer0) then gin1 (layer1)

    prep_kernel<<<256,256,0,stream>>>(Wih0,Whh0,Wih1,Whh1,bih0,bhh0,bih1,bhh1,
                                      Aswz0,Aswz1,WhhT0,WhhT1);
    gin0_kernel<<<Rc/128,256,0,stream>>>(word_idx,pos_idx,dep_idx,dir_idx,
                                         word_emb,pos_emb,dep_emb,dir_emb,
                                         Aswz0,ginbuf);
    rec0_kernel<<<Nc/64,512,0,stream>>>(ginbuf,WhhT0,h1R);
    gin1_kernel<<<Rc/128,256,0,stream>>>(h1R,Aswz1,ginbuf);
    rec1_kernel<<<Nc/64,512,0,stream>>>(ginbuf,WhhT1,lengths,lastT);
    final_kernel<<<Bc,320,0,stream>>>(lastT,counts,pair_idx,word_emb,W,bvec,out);
}

// Round 4
// 693.688 us; speedup vs baseline: 1.2738x; 1.2738x over previous
//
#include <hip/hip_runtime.h>
#include <math.h>

#define ED 300
#define Hh 60
#define G4 240
#define NRELc 5
#define Bc 1024
#define Pc 16
#define Lc 8
#define Nc (Bc*Pc)        /* 16384 sequences */
#define Rc (Nc*Lc)        /* 131072 rows, r = t*Nc + n */
#define VOC 50000
#define TROW 256          /* u16 per concat-table row (512B) */
#define POS0 50000
#define DEP0 50050
#define DIR0 50100
#define NTROWS 50104

typedef __attribute__((ext_vector_type(8))) short short8v;
typedef __attribute__((ext_vector_type(4))) unsigned short ushort4v;
typedef __attribute__((ext_vector_type(4))) float f32x4;
typedef unsigned short u16;

__device__ __forceinline__ float sigf(float x){ return 1.f/(1.f+__expf(-x)); }
__device__ __forceinline__ float tanhfast(float x){
    x = fminf(fmaxf(x,-15.f),15.f);
    float e = __expf(-2.f*x);
    return (1.f-e)/(1.f+e);
}
__device__ __forceinline__ u16 f2b(float f){        // fp32 -> bf16 bits, RNE
    union{float f; unsigned u;} v; v.f=f;
    unsigned r = v.u + 0x7fffu + ((v.u>>16)&1u);
    return (u16)(r>>16);
}
__device__ __forceinline__ float b2f(u16 b){ return __uint_as_float(((unsigned)b)<<16); }
__device__ __forceinline__ float blo(unsigned d){ return __uint_as_float(d<<16); }
__device__ __forceinline__ float bhi(unsigned d){ return __uint_as_float(d & 0xffff0000u); }

// Aswz frag layout (verified R3): lane l, elem e -> j = m*16+(l&15),
// k = ks*32 + 16*(e>>2) + 4*(l>>4) + (e&3).
__global__ __launch_bounds__(256) void prep_kernel(
    const float* __restrict__ Wih0, const float* __restrict__ Whh0,
    const float* __restrict__ Wih1, const float* __restrict__ Whh1,
    const float* __restrict__ bih0, const float* __restrict__ bhh0,
    const float* __restrict__ bih1, const float* __restrict__ bhh1,
    const float* __restrict__ pemb, const float* __restrict__ demb,
    const float* __restrict__ remb,
    u16* __restrict__ Aswz0, u16* __restrict__ Aswz1,
    float* __restrict__ WhhT0, float* __restrict__ WhhT1,
    u16* __restrict__ tab)
{
    const int i0 = blockIdx.x*256 + threadIdx.x;
    const int stride = gridDim.x*256;
    for (int idx=i0; idx<15*10*64*8; idx+=stride){
        int e = idx&7, l = (idx>>3)&63, mk = idx>>9;
        int m = mk/10, ks = mk - m*10;
        int j = m*16 + (l&15);
        int k = ks*32 + ((e>>2)<<4) + ((l>>4)<<2) + (e&3);
        float v = 0.f;
        if (k < 310)      v = Wih0[j*310 + k];
        else if (k==310)  v = bih0[j] + bhh0[j];
        Aswz0[idx] = f2b(v);
    }
    for (int idx=i0; idx<15*2*64*8; idx+=stride){
        int e = idx&7, l = (idx>>3)&63, mk = idx>>9;
        int m = mk>>1, ks = mk&1;
        int j = m*16 + (l&15);
        int k = ks*32 + ((e>>2)<<4) + ((l>>4)<<2) + (e&3);
        float v = 0.f;
        if (k < 60)       v = Wih1[j*60 + k];
        else if (k==60)   v = bih1[j] + bhh1[j];
        Aswz1[idx] = f2b(v);
    }
    for (int idx=i0; idx<60*240; idx+=stride){
        int k = idx/240, j = idx - k*240;
        WhhT0[idx] = Whh0[j*60 + k];
        WhhT1[idx] = Whh1[j*60 + k];
    }
    // small tables: pos (rows POS0+p), dep (DEP0+d), dir+bias (DIR0+dd)
    for (int idx=i0; idx<50*240; idx+=stride){
        int p = idx/240, j = idx - p*240;
        float v = 0.f;
        for (int q=0;q<4;q++) v += Wih0[j*310 + 300+q]*pemb[p*4+q];
        tab[(size_t)(POS0+p)*TROW + j] = f2b(v);
        float w = 0.f;
        for (int q=0;q<5;q++) w += Wih0[j*310 + 304+q]*demb[p*5+q];
        tab[(size_t)(DEP0+p)*TROW + j] = f2b(w);
    }
    for (int idx=i0; idx<4*240; idx+=stride){
        int d = idx/240, j = idx - d*240;
        float v = remb[d]*Wih0[j*310 + 309] + bih0[j] + bhh0[j];
        tab[(size_t)(DIR0+d)*TROW + j] = f2b(v);
    }
}

// Vocab precompute: tab[v][j] = sum_{k<300} Wih0[j][k] * wemb[v][k].
// B-fragments straight from global (k-chunks are aligned float4s). No LDS.
__global__ __launch_bounds__(256,2) void wxa_kernel(
    const float* __restrict__ wemb, const u16* __restrict__ Aswz,
    u16* __restrict__ tab)
{
    const int tid = threadIdx.x;
    const int l  = tid & 63;
    const int wv = __builtin_amdgcn_readfirstlane(tid>>6);
    const int r0 = blockIdx.x*128;
    const int row0 = wv*32 + (l&15);
    const int v0 = r0 + row0, v1 = v0 + 16;
    const int v0c = v0 < VOC ? v0 : VOC-1;
    const int v1c = v1 < VOC ? v1 : VOC-1;
    const float* b0p = wemb + (size_t)v0c*300;
    const float* b1p = wemb + (size_t)v1c*300;

    f32x4 acc[15][2];
#pragma unroll
    for (int m=0;m<15;m++){
        acc[m][0] = f32x4{0.f,0.f,0.f,0.f};
        acc[m][1] = f32x4{0.f,0.f,0.f,0.f};
    }
    const float4 z4 = {0.f,0.f,0.f,0.f};

#pragma unroll
    for (int ks=0; ks<10; ++ks){
        const int k0 = ks*32 + ((l>>4)<<2);
        const int k1 = k0 + 16;
        float4 a0 = (k0<300) ? *(const float4*)(b0p+k0) : z4;
        float4 a1 = (k1<300) ? *(const float4*)(b0p+k1) : z4;
        float4 c0 = (k0<300) ? *(const float4*)(b1p+k0) : z4;
        float4 c1 = (k1<300) ? *(const float4*)(b1p+k1) : z4;
        short8v bf0 = {(short)f2b(a0.x),(short)f2b(a0.y),(short)f2b(a0.z),(short)f2b(a0.w),
                       (short)f2b(a1.x),(short)f2b(a1.y),(short)f2b(a1.z),(short)f2b(a1.w)};
        short8v bf1 = {(short)f2b(c0.x),(short)f2b(c0.y),(short)f2b(c0.z),(short)f2b(c0.w),
                       (short)f2b(c1.x),(short)f2b(c1.y),(short)f2b(c1.z),(short)f2b(c1.w)};
#pragma unroll
        for (int m=0;m<15;m++){
            short8v a = *(const short8v*)(Aswz + (size_t)(((m*10+ks)<<6) + l)*8);
            acc[m][0] = __builtin_amdgcn_mfma_f32_16x16x32_bf16(a, bf0, acc[m][0], 0,0,0);
            acc[m][1] = __builtin_amdgcn_mfma_f32_16x16x32_bf16(a, bf1, acc[m][1], 0,0,0);
        }
    }
#pragma unroll
    for (int m=0;m<15;m++){
        const int j = m*16 + ((l>>4)<<2);
        ushort4v s0, s1;
#pragma unroll
        for (int i=0;i<4;i++){ s0[i]=f2b(acc[m][0][i]); s1[i]=f2b(acc[m][1][i]); }
        if (v0 < VOC) *(ushort4v*)(tab + (size_t)v0*TROW + j) = s0;
        if (v1 < VOC) *(ushort4v*)(tab + (size_t)v1*TROW + j) = s1;
    }
}

// gin0[j][r] = tab[w[r]][j] + tab[POS0+p][j] + tab[DEP0+d][j] + tab[DIR0+dir][j]
// (dir row includes bias). Lane = row r (coalesced stores), wave = 60-j chunk.
__global__ __launch_bounds__(256,4) void gadd_kernel(
    const int* __restrict__ widx, const int* __restrict__ pidx,
    const int* __restrict__ didx, const int* __restrict__ ridx,
    const u16* __restrict__ tab, u16* __restrict__ gin)
{
    const int tid = threadIdx.x;
    const int l  = tid & 63;
    const int wv = tid >> 6;
    const int r  = blockIdx.x*64 + l;
    const int n = r & (Nc-1), t = r >> 14;
    const int w  = widx[n*Lc+t];
    const int p  = pidx[n*Lc+t];
    const int d  = didx[n*Lc+t];
    const int dd = ridx[n*Lc+t];
    const uint2* rw = (const uint2*)(tab + (size_t)w*TROW        + wv*60);
    const uint2* rp = (const uint2*)(tab + (size_t)(POS0+p)*TROW + wv*60);
    const uint2* rd = (const uint2*)(tab + (size_t)(DEP0+d)*TROW + wv*60);
    const uint2* rr = (const uint2*)(tab + (size_t)(DIR0+dd)*TROW+ wv*60);

    float acc[60];
#pragma unroll
    for (int i=0;i<15;i++){
        uint2 aw = rw[i], ap = rp[i], ad = rd[i], ar = rr[i];
        acc[4*i+0] = blo(aw.x)+blo(ap.x)+blo(ad.x)+blo(ar.x);
        acc[4*i+1] = bhi(aw.x)+bhi(ap.x)+bhi(ad.x)+bhi(ar.x);
        acc[4*i+2] = blo(aw.y)+blo(ap.y)+blo(ad.y)+blo(ar.y);
        acc[4*i+3] = bhi(aw.y)+bhi(ap.y)+bhi(ad.y)+bhi(ar.y);
    }
    u16* gb = gin + (size_t)(wv*60)*Rc + r;
#pragma unroll
    for (int jj=0;jj<60;jj++) gb[(size_t)jj*Rc] = f2b(acc[jj]);
}

// gin1 = [bias|Wih1] @ h1^T via MFMA, B-frags direct from global h1R rows.
__global__ __launch_bounds__(256,2) void gin1_kernel(
    const u16* __restrict__ h1R, const u16* __restrict__ Aswz, u16* __restrict__ gout)
{
    const int tid = threadIdx.x;
    const int l  = tid & 63;
    const int wv = __builtin_amdgcn_readfirstlane(tid>>6);
    const int r0 = blockIdx.x*128;
    const int row0 = wv*32 + (l&15);
    const size_t rb0 = (size_t)(r0+row0)<<6;
    const size_t rb1 = rb0 + (16<<6);

    f32x4 acc[15][2];
#pragma unroll
    for (int m=0;m<15;m++){
        acc[m][0] = f32x4{0.f,0.f,0.f,0.f};
        acc[m][1] = f32x4{0.f,0.f,0.f,0.f};
    }
#pragma unroll
    for (int ks=0; ks<2; ++ks){
        const int off = ks*32 + ((l>>4)<<2);
        ushort4v lo0 = *(const ushort4v*)(h1R + rb0 + off);
        ushort4v hi0 = *(const ushort4v*)(h1R + rb0 + off + 16);
        ushort4v lo1 = *(const ushort4v*)(h1R + rb1 + off);
        ushort4v hi1 = *(const ushort4v*)(h1R + rb1 + off + 16);
        short8v bf0 = {(short)lo0[0],(short)lo0[1],(short)lo0[2],(short)lo0[3],
                       (short)hi0[0],(short)hi0[1],(short)hi0[2],(short)hi0[3]};
        short8v bf1 = {(short)lo1[0],(short)lo1[1],(short)lo1[2],(short)lo1[3],
                       (short)hi1[0],(short)hi1[1],(short)hi1[2],(short)hi1[3]};
#pragma unroll
        for (int m=0;m<15;m++){
            short8v a = *(const short8v*)(Aswz + (size_t)((((m<<1)+ks)<<6) + l)*8);
            acc[m][0] = __builtin_amdgcn_mfma_f32_16x16x32_bf16(a, bf0, acc[m][0], 0,0,0);
            acc[m][1] = __builtin_amdgcn_mfma_f32_16x16x32_bf16(a, bf1, acc[m][1], 0,0,0);
        }
    }
    const int rA = r0 + row0;
#pragma unroll
    for (int m=0;m<15;m++){
#pragma unroll
        for (int i=0;i<4;i++){
            int j = m*16 + ((l>>4)<<2) + i;
            gout[(size_t)j*Rc + rA]      = f2b(acc[m][0][i]);
            gout[(size_t)j*Rc + rA + 16] = f2b(acc[m][1][i]);
        }
    }
}

// Layer-0 recurrence (verbatim R3). 8 waves: wave (g=wv>>1, half=wv&1) = 30 gate rows.
__global__ __launch_bounds__(512,2) void rec0_kernel(
    const u16* __restrict__ gin, const float* __restrict__ WhhT, u16* __restrict__ h1R)
{
    __shared__ float hlds[64][60];
    __shared__ float gact[4][60][64];
    const int tid = threadIdx.x;
    const int l   = tid & 63;
    const int wv  = __builtin_amdgcn_readfirstlane(tid>>6);
    const int g = wv>>1, hf = wv&1;
    const int n0 = blockIdx.x*64;

    for (int idx=tid; idx<64*60; idx+=512) ((float*)hlds)[idx]=0.f;
    float c_reg[8];
#pragma unroll
    for (int i=0;i<8;i++) c_reg[i]=0.f;
    __syncthreads();

    const u16*  gb0 = gin + (size_t)(g*60+hf*30)*Rc + n0 + l;
    const float* wb = WhhT + g*60 + hf*30;

    for (int t=0;t<Lc;t++){
        float acc[30];
        const u16* gb = gb0 + (size_t)t*Nc;
#pragma unroll
        for (int i=0;i<30;i++) acc[i] = b2f(gb[(size_t)i*Rc]);
#pragma unroll
        for (int k4=0;k4<15;k4++){
            float4 h4 = *(const float4*)&hlds[l][k4*4];
            const float* w0 = wb + (k4*4+0)*G4;
            const float* w1 = wb + (k4*4+1)*G4;
            const float* w2 = wb + (k4*4+2)*G4;
            const float* w3 = wb + (k4*4+3)*G4;
#pragma unroll
            for (int i=0;i<30;i++) acc[i] += w0[i]*h4.x + w1[i]*h4.y + w2[i]*h4.z + w3[i]*h4.w;
        }
        if (g==2){
#pragma unroll
            for (int i=0;i<30;i++) gact[2][hf*30+i][l] = tanhfast(acc[i]);
        } else {
#pragma unroll
            for (int i=0;i<30;i++) gact[g][hf*30+i][l] = sigf(acc[i]);
        }
        __syncthreads();
#pragma unroll
        for (int i=0;i<8;i++){
            int u = wv + 8*i;
            if (u < 60){
                float iv = gact[0][u][l], fv = gact[1][u][l];
                float gv = gact[2][u][l], ov = gact[3][u][l];
                float c = fv*c_reg[i] + iv*gv;
                c_reg[i] = c;
                hlds[l][u] = ov*tanhfast(c);
            }
        }
        __syncthreads();
#pragma unroll
        for (int it=0; it<8; ++it){
            int nl = it*8 + wv;
            float v = (l<60) ? hlds[nl][l] : ((l==60)?1.f:0.f);
            h1R[((size_t)(t*Nc + n0 + nl)<<6) + l] = f2b(v);
        }
        __syncthreads();
    }
}

// Layer-1 recurrence (verbatim R3); h2 at t==len-1 -> lastT[u][n].
__global__ __launch_bounds__(512,2) void rec1_kernel(
    const u16* __restrict__ gin, const float* __restrict__ WhhT,
    const int* __restrict__ lens, float* __restrict__ lastT)
{
    __shared__ float hlds[64][60];
    __shared__ float gact[4][60][64];
    const int tid = threadIdx.x;
    const int l   = tid & 63;
    const int wv  = __builtin_amdgcn_readfirstlane(tid>>6);
    const int g = wv>>1, hf = wv&1;
    const int n0 = blockIdx.x*64;
    const int mylen = lens[n0+l];

    for (int idx=tid; idx<64*60; idx+=512) ((float*)hlds)[idx]=0.f;
    float c_reg[8];
#pragma unroll
    for (int i=0;i<8;i++) c_reg[i]=0.f;
    __syncthreads();

    const u16*  gb0 = gin + (size_t)(g*60+hf*30)*Rc + n0 + l;
    const float* wb = WhhT + g*60 + hf*30;

    for (int t=0;t<Lc;t++){
        float acc[30];
        const u16* gb = gb0 + (size_t)t*Nc;
#pragma unroll
        for (int i=0;i<30;i++) acc[i] = b2f(gb[(size_t)i*Rc]);
#pragma unroll
        for (int k4=0;k4<15;k4++){
            float4 h4 = *(const float4*)&hlds[l][k4*4];
            const float* w0 = wb + (k4*4+0)*G4;
            const float* w1 = wb + (k4*4+1)*G4;
            const float* w2 = wb + (k4*4+2)*G4;
            const float* w3 = wb + (k4*4+3)*G4;
#pragma unroll
            for (int i=0;i<30;i++) acc[i] += w0[i]*h4.x + w1[i]*h4.y + w2[i]*h4.z + w3[i]*h4.w;
        }
        if (g==2){
#pragma unroll
            for (int i=0;i<30;i++) gact[2][hf*30+i][l] = tanhfast(acc[i]);
        } else {
#pragma unroll
            for (int i=0;i<30;i++) gact[g][hf*30+i][l] = sigf(acc[i]);
        }
        __syncthreads();
#pragma unroll
        for (int i=0;i<8;i++){
            int u = wv + 8*i;
            if (u < 60){
                float iv = gact[0][u][l], fv = gact[1][u][l];
                float gv = gact[2][u][l], ov = gact[3][u][l];
                float c = fv*c_reg[i] + iv*gv;
                c_reg[i] = c;
                float h = ov*tanhfast(c);
                hlds[l][u] = h;
                if (t == mylen-1) lastT[(size_t)u*Nc + n0 + l] = h;
            }
        }
        __syncthreads();
    }
}

// Mean over P, concat [xw, path, yw] @ W^T + b, softmax. One block per batch row.
__global__ __launch_bounds__(320) void final_kernel(
    const float* __restrict__ lastT, const float* __restrict__ counts,
    const int* __restrict__ pair, const float* __restrict__ wemb,
    const float* __restrict__ W, const float* __restrict__ bvec,
    float* __restrict__ out)
{
    __shared__ float path[Hh];
    __shared__ float red[NRELc];
    const int b = blockIdx.x;
    const int tid = threadIdx.x;

    if (tid < Hh){
        float s=0.f, cs=0.f;
        for (int p=0;p<Pc;p++){
            float cnt = counts[b*Pc+p];
            s  += lastT[(size_t)tid*Nc + b*Pc+p]*cnt;
            cs += cnt;
        }
        path[tid] = s/cs;
    }
    __syncthreads();

    const int rrel = tid>>6;
    const int lane = tid&63;
    const int xi = pair[b*2+0], yi = pair[b*2+1];
    const float* Wr = W + rrel*(2*ED+Hh);
    float acc=0.f;
    for (int d=lane; d<ED; d+=64) acc += wemb[xi*ED+d]*Wr[d];
    for (int k=lane; k<Hh; k+=64) acc += path[k]*Wr[ED+k];
    for (int d=lane; d<ED; d+=64) acc += wemb[yi*ED+d]*Wr[ED+Hh+d];
    for (int off=32; off>0; off>>=1) acc += __shfl_down(acc, off);
    if (lane==0) red[rrel] = acc + bvec[rrel];
    __syncthreads();

    if (tid==0){
        float m=red[0];
        for (int i=1;i<NRELc;i++) m=fmaxf(m,red[i]);
        float e[NRELc]; float s=0.f;
        for (int i=0;i<NRELc;i++){ e[i]=__expf(red[i]-m); s+=e[i]; }
        float inv=1.f/s;
        for (int i=0;i<NRELc;i++) out[b*NRELc+i]=e[i]*inv;
    }
}

extern "C" void kernel_launch(void* const* d_in, const int* in_sizes, int n_in,
                              void* d_out, int out_size, void* d_ws, size_t ws_size,
                              hipStream_t stream)
{
    const int*   word_idx = (const int*)d_in[0];
    const int*   pos_idx  = (const int*)d_in[1];
    const int*   dep_idx  = (const int*)d_in[2];
    const int*   dir_idx  = (const int*)d_in[3];
    const int*   lengths  = (const int*)d_in[4];
    const float* counts   = (const float*)d_in[5];
    const int*   pair_idx = (const int*)d_in[6];
    const float* word_emb = (const float*)d_in[7];
    const float* pos_emb  = (const float*)d_in[8];
    const float* dep_emb  = (const float*)d_in[9];
    const float* dir_emb  = (const float*)d_in[10];
    const float* Wih0     = (const float*)d_in[11];
    const float* Whh0     = (const float*)d_in[12];
    const float* bih0     = (const float*)d_in[13];
    const float* bhh0     = (const float*)d_in[14];
    const float* Wih1     = (const float*)d_in[15];
    const float* Whh1     = (const float*)d_in[16];
    const float* bih1     = (const float*)d_in[17];
    const float* bhh1     = (const float*)d_in[18];
    const float* W        = (const float*)d_in[19];
    const float* bvec     = (const float*)d_in[20];
    float* out = (float*)d_out;

    // Workspace (~110 MB): fp32 region, then u16 region.
    float* p = (float*)d_ws;
    float* WhhT0 = p; p += 60*G4;
    float* WhhT1 = p; p += 60*G4;
    float* lastT = p; p += (size_t)Nc*Hh;
    u16* q = (u16*)p;
    u16* Aswz0 = q; q += 15*10*64*8;
    u16* Aswz1 = q; q += 15*2*64*8;
    u16* h1R   = q; q += (size_t)Rc*64;
    u16* gin   = q; q += (size_t)G4*Rc;   // shared by layer0 then layer1 pre-acts
    u16* tab   = q; q += (size_t)NTROWS*TROW;

    prep_kernel<<<256,256,0,stream>>>(Wih0,Whh0,Wih1,Whh1,bih0,bhh0,bih1,bhh1,
                                      pos_emb,dep_emb,dir_emb,
                                      Aswz0,Aswz1,WhhT0,WhhT1,tab);
    wxa_kernel<<<(VOC+127)/128,256,0,stream>>>(word_emb,Aswz0,tab);
    gadd_kernel<<<Rc/64,256,0,stream>>>(word_idx,pos_idx,dep_idx,dir_idx,tab,gin);
    rec0_kernel<<<Nc/64,512,0,stream>>>(gin,WhhT0,h1R);
    gin1_kernel<<<Rc/128,256,0,stream>>>(h1R,Aswz1,gin);
    rec1_kernel<<<Nc/64,512,0,stream>>>(gin,WhhT1,lengths,lastT);
    final_kernel<<<Bc,320,0,stream>>>(lastT,counts,pair_idx,word_emb,W,bvec,out);
}

// Round 5
// 394.999 us; speedup vs baseline: 2.2370x; 1.7562x over previous
//
#include <hip/hip_runtime.h>
#include <math.h>

#define ED 300
#define Hh 60
#define G4 240
#define NRELc 5
#define Bc 1024
#define Pc 16
#define Lc 8
#define Nc (Bc*Pc)        /* 16384 sequences */
#define Rc (Nc*Lc)        /* 131072 rows, r = t*Nc + n */
#define VOC 50000
#define TROW 256          /* u16 per table row (512B) */
#define POS0 50000
#define DEP0 50050
#define DIR0 50100
#define NTROWS 50104
#define NTILES 8192       /* Rc/16 */

typedef __attribute__((ext_vector_type(8))) short short8v;
typedef __attribute__((ext_vector_type(4))) unsigned short ushort4v;
typedef __attribute__((ext_vector_type(4))) float f32x4;
typedef unsigned short u16;

__device__ __forceinline__ float tanhfast(float x){
    x = fminf(fmaxf(x,-15.f),15.f);
    float e = __expf(-2.f*x);
    return (1.f-e)/(1.f+e);
}
__device__ __forceinline__ u16 f2b(float f){        // fp32 -> bf16 bits, RNE
    union{float f; unsigned u;} v; v.f=f;
    unsigned r = v.u + 0x7fffu + ((v.u>>16)&1u);
    return (u16)(r>>16);
}
__device__ __forceinline__ float b2f(u16 b){ return __uint_as_float(((unsigned)b)<<16); }
__device__ __forceinline__ float blo(unsigned d){ return __uint_as_float(d<<16); }
__device__ __forceinline__ float bhi(unsigned d){ return __uint_as_float(d & 0xffff0000u); }

// A-frag layout (R3-verified): lane l, elem e -> j = m*16+(l&15),
// k = ks*32 + 16*(e>>2) + 4*(l>>4) + (e&3).
__global__ __launch_bounds__(256) void prep_kernel(
    const float* __restrict__ Wih0, const float* __restrict__ Whh0,
    const float* __restrict__ Wih1, const float* __restrict__ Whh1,
    const float* __restrict__ bih0, const float* __restrict__ bhh0,
    const float* __restrict__ bih1, const float* __restrict__ bhh1,
    const float* __restrict__ pemb, const float* __restrict__ demb,
    const float* __restrict__ remb,
    u16* __restrict__ Aswz0, u16* __restrict__ A0F, u16* __restrict__ A1F,
    u16* __restrict__ tab)
{
    const int i0 = blockIdx.x*256 + threadIdx.x;
    const int stride = gridDim.x*256;
    // wxa A-frags: K=320 (310 real + bias@310)
    for (int idx=i0; idx<15*10*64*8; idx+=stride){
        int e = idx&7, l = (idx>>3)&63, mk = idx>>9;
        int m = mk/10, ks = mk - m*10;
        int j = m*16 + (l&15);
        int k = ks*32 + ((e>>2)<<4) + ((l>>4)<<2) + (e&3);
        float v = 0.f;
        if (k < 310)      v = Wih0[j*310 + k];
        else if (k==310)  v = bih0[j] + bhh0[j];
        Aswz0[idx] = f2b(v);
    }
    // recurrence layer0 A: Whh0, K=64 (rows 60..63 zero)
    for (int idx=i0; idx<15*2*64*8; idx+=stride){
        int e = idx&7, l = (idx>>3)&63, mk = idx>>9;
        int m = mk>>1, ks = mk&1;
        int j = m*16 + (l&15);
        int k = ks*32 + ((e>>2)<<4) + ((l>>4)<<2) + (e&3);
        A0F[idx] = f2b(k<60 ? Whh0[j*60+k] : 0.f);
    }
    // layer1 A: [Wih1 | bias@60 | 0 | Whh1@64..123 | 0], K=128
    for (int idx=i0; idx<15*4*64*8; idx+=stride){
        int e = idx&7, l = (idx>>3)&63, mk = idx>>9;
        int m = mk>>2, ks = mk&3;
        int j = m*16 + (l&15);
        int k = ks*32 + ((e>>2)<<4) + ((l>>4)<<2) + (e&3);
        float v = 0.f;
        if (k < 60)                 v = Wih1[j*60 + k];
        else if (k == 60)           v = bih1[j] + bhh1[j];
        else if (k >= 64 && k < 124) v = Whh1[j*60 + (k-64)];
        A1F[idx] = f2b(v);
    }
    // small tables: pos / dep / dir(+bias0)
    for (int idx=i0; idx<50*240; idx+=stride){
        int p = idx/240, j = idx - p*240;
        float v = 0.f;
        for (int q=0;q<4;q++) v += Wih0[j*310 + 300+q]*pemb[p*4+q];
        tab[(size_t)(POS0+p)*TROW + j] = f2b(v);
        float w = 0.f;
        for (int q=0;q<5;q++) w += Wih0[j*310 + 304+q]*demb[p*5+q];
        tab[(size_t)(DEP0+p)*TROW + j] = f2b(w);
    }
    for (int idx=i0; idx<4*240; idx+=stride){
        int d = idx/240, j = idx - d*240;
        float v = remb[d]*Wih0[j*310 + 309] + bih0[j] + bhh0[j];
        tab[(size_t)(DIR0+d)*TROW + j] = f2b(v);
    }
}

// Vocab precompute (unchanged R4): tab[v][j] = sum_k Wih0[j][k]*wemb[v][k].
__global__ __launch_bounds__(256,2) void wxa_kernel(
    const float* __restrict__ wemb, const u16* __restrict__ Aswz,
    u16* __restrict__ tab)
{
    const int tid = threadIdx.x;
    const int l  = tid & 63;
    const int wv = __builtin_amdgcn_readfirstlane(tid>>6);
    const int r0 = blockIdx.x*128;
    const int row0 = wv*32 + (l&15);
    const int v0 = r0 + row0, v1 = v0 + 16;
    const int v0c = v0 < VOC ? v0 : VOC-1;
    const int v1c = v1 < VOC ? v1 : VOC-1;
    const float* b0p = wemb + (size_t)v0c*300;
    const float* b1p = wemb + (size_t)v1c*300;

    f32x4 acc[15][2];
#pragma unroll
    for (int m=0;m<15;m++){
        acc[m][0] = f32x4{0.f,0.f,0.f,0.f};
        acc[m][1] = f32x4{0.f,0.f,0.f,0.f};
    }
    const float4 z4 = {0.f,0.f,0.f,0.f};
#pragma unroll
    for (int ks=0; ks<10; ++ks){
        const int k0 = ks*32 + ((l>>4)<<2);
        const int k1 = k0 + 16;
        float4 a0 = (k0<300) ? *(const float4*)(b0p+k0) : z4;
        float4 a1 = (k1<300) ? *(const float4*)(b0p+k1) : z4;
        float4 c0 = (k0<300) ? *(const float4*)(b1p+k0) : z4;
        float4 c1 = (k1<300) ? *(const float4*)(b1p+k1) : z4;
        short8v bf0 = {(short)f2b(a0.x),(short)f2b(a0.y),(short)f2b(a0.z),(short)f2b(a0.w),
                       (short)f2b(a1.x),(short)f2b(a1.y),(short)f2b(a1.z),(short)f2b(a1.w)};
        short8v bf1 = {(short)f2b(c0.x),(short)f2b(c0.y),(short)f2b(c0.z),(short)f2b(c0.w),
                       (short)f2b(c1.x),(short)f2b(c1.y),(short)f2b(c1.z),(short)f2b(c1.w)};
#pragma unroll
        for (int m=0;m<15;m++){
            short8v a = *(const short8v*)(Aswz + (size_t)(((m*10+ks)<<6) + l)*8);
            acc[m][0] = __builtin_amdgcn_mfma_f32_16x16x32_bf16(a, bf0, acc[m][0], 0,0,0);
            acc[m][1] = __builtin_amdgcn_mfma_f32_16x16x32_bf16(a, bf1, acc[m][1], 0,0,0);
        }
    }
#pragma unroll
    for (int m=0;m<15;m++){
        const int j = m*16 + ((l>>4)<<2);
        ushort4v s0, s1;
#pragma unroll
        for (int i=0;i<4;i++){ s0[i]=f2b(acc[m][0][i]); s1[i]=f2b(acc[m][1][i]); }
        if (v0 < VOC) *(ushort4v*)(tab + (size_t)v0*TROW + j) = s0;
        if (v1 < VOC) *(ushort4v*)(tab + (size_t)v1*TROW + j) = s1;
    }
}

// gin0 in C-FRAG order: ginF[(s*15+m)*256 + l*4 + i] = gin0[j][r],
// j = m*16+4*(l>>4)+i, r = s*16+(l&15) over tiles s (t = s>>10).
__global__ __launch_bounds__(256,4) void gadd_kernel(
    const int* __restrict__ widx, const int* __restrict__ pidx,
    const int* __restrict__ didx, const int* __restrict__ ridx,
    const u16* __restrict__ tab, u16* __restrict__ ginF)
{
    const int tid = threadIdx.x;
    const int l  = tid & 63;
    const int wv = tid >> 6;
    const int s  = blockIdx.x*4 + wv;      // 0..8191
    const int t  = s >> 10;
    const int n  = ((s & 1023)<<4) + (l&15);
    const int w  = widx[n*Lc+t];
    const int p  = pidx[n*Lc+t];
    const int d  = didx[n*Lc+t];
    const int dd = ridx[n*Lc+t];
    const u16* rw = tab + (size_t)w*TROW;
    const u16* rp = tab + (size_t)(POS0+p)*TROW;
    const u16* rd = tab + (size_t)(DEP0+d)*TROW;
    const u16* rr = tab + (size_t)(DIR0+dd)*TROW;
    const int j0 = (l>>4)<<2;

#pragma unroll
    for (int m=0;m<15;m++){
        const int j = m*16 + j0;
        uint2 aw = *(const uint2*)(rw + j);
        uint2 ap = *(const uint2*)(rp + j);
        uint2 ad = *(const uint2*)(rd + j);
        uint2 ar = *(const uint2*)(rr + j);
        ushort4v o;
        o[0] = f2b(blo(aw.x)+blo(ap.x)+blo(ad.x)+blo(ar.x));
        o[1] = f2b(bhi(aw.x)+bhi(ap.x)+bhi(ad.x)+bhi(ar.x));
        o[2] = f2b(blo(aw.y)+blo(ap.y)+blo(ad.y)+blo(ar.y));
        o[3] = f2b(bhi(aw.y)+bhi(ap.y)+bhi(ad.y)+bhi(ar.y));
        *(ushort4v*)(ginF + (((size_t)s*15+m)<<8) + (l<<2)) = o;
    }
}

// Fused 2-layer LSTM recurrence via MFMA. Block = 64 seqs, 4 waves (wave = n-tile).
// Per t: gates0 = ginF + Whh0*h1  -> h1;  gates1 = [Wih1|b|Whh1]*[h1;1;h2] -> h2.
__global__ __launch_bounds__(256,1) void recf_kernel(
    const u16* __restrict__ ginF, const u16* __restrict__ A0F,
    const u16* __restrict__ A1F, const int* __restrict__ lens,
    float* __restrict__ lastT)
{
    __shared__ u16 hT0[64][66];     // layer0 state h1 (bf16), row60 = 1.0
    __shared__ u16 hT2[64][66];     // layer1 state h2
    __shared__ u16 gact[64][244];   // activated gates, [n][j]
    const int tid = threadIdx.x;
    const int l  = tid & 63;
    const int w  = __builtin_amdgcn_readfirstlane(tid>>6);
    const int n0 = blockIdx.x*64;
    const int nn = w*16 + (l&15);   // B/C column (seq within block)
    const int jo = (l>>4)<<2;       // C row offset within m-tile
    const int mylen = lens[n0 + l];

    for (int idx=tid; idx<64*66; idx+=256){ ((u16*)hT0)[idx]=0; ((u16*)hT2)[idx]=0; }
    __syncthreads();
    if (tid < 64) hT0[60][tid] = 0x3F80;   // bias row = 1.0
    float c1[15], c2[15];
#pragma unroll
    for (int i=0;i<15;i++){ c1[i]=0.f; c2[i]=0.f; }
    __syncthreads();

    const int sbase = blockIdx.x*4 + w;

    for (int t=0;t<Lc;t++){
        const size_t s = (size_t)t*1024 + sbase;
        f32x4 acc[15];
        // acc init from ginF (coalesced 8B/lane)
#pragma unroll
        for (int m=0;m<15;m++){
            ushort4v g4 = *(const ushort4v*)(ginF + (((size_t)s*15+m)<<8) + (l<<2));
            acc[m] = f32x4{ b2f(g4[0]), b2f(g4[1]), b2f(g4[2]), b2f(g4[3]) };
        }
        // GEMM0: += Whh0 * h1(t-1)
#pragma unroll
        for (int ks=0;ks<2;ks++){
            short8v b;
#pragma unroll
            for (int e=0;e<8;e++){
                int k = ks*32 + ((e>>2)<<4) + jo + (e&3);
                b[e] = (short)hT0[k][nn];
            }
#pragma unroll
            for (int m=0;m<15;m++){
                short8v a = *(const short8v*)(A0F + (size_t)(((m*2+ks)*64 + l)*8));
                acc[m] = __builtin_amdgcn_mfma_f32_16x16x32_bf16(a, b, acc[m], 0,0,0);
            }
        }
        // gates0 activation -> gact[n][j]
#pragma unroll
        for (int m=0;m<15;m++){
            ushort4v o;
#pragma unroll
            for (int i=0;i<4;i++){
                int j = m*16 + jo + i;
                float x = fminf(fmaxf(acc[m][i],-30.f),30.f);
                bool th = (j>=120)&&(j<180);
                float e = __expf(th ? -2.f*x : -x);
                float numv = th ? (1.f-e) : 1.f;
                o[i] = f2b(numv/(1.f+e));
            }
            *(ushort4v*)&gact[nn][m*16 + jo] = o;
        }
        __syncthreads();
        // c1/h1 update: thread (w,l) owns u = w*15+i, seq n = l
#pragma unroll
        for (int i=0;i<15;i++){
            int u = w*15 + i;
            float gi = b2f(gact[l][u]);
            float gf = b2f(gact[l][60+u]);
            float gg = b2f(gact[l][120+u]);
            float go = b2f(gact[l][180+u]);
            float c = gf*c1[i] + gi*gg;
            c1[i] = c;
            hT0[u][l] = f2b(go*tanhfast(c));
        }
        __syncthreads();
        // GEMM1: gates1 = [Wih1|bias|Whh1] * [h1(t);1;0;h2(t-1);0]
#pragma unroll
        for (int m=0;m<15;m++) acc[m] = f32x4{0.f,0.f,0.f,0.f};
#pragma unroll
        for (int ks=0;ks<4;ks++){
            short8v b;
#pragma unroll
            for (int e=0;e<8;e++){
                int kk = (ks&1)*32 + ((e>>2)<<4) + jo + (e&3);
                b[e] = (short)((ks<2) ? hT0[kk][nn] : hT2[kk][nn]);
            }
#pragma unroll
            for (int m=0;m<15;m++){
                short8v a = *(const short8v*)(A1F + (size_t)(((m*4+ks)*64 + l)*8));
                acc[m] = __builtin_amdgcn_mfma_f32_16x16x32_bf16(a, b, acc[m], 0,0,0);
            }
        }
        // gates1 activation -> gact
#pragma unroll
        for (int m=0;m<15;m++){
            ushort4v o;
#pragma unroll
            for (int i=0;i<4;i++){
                int j = m*16 + jo + i;
                float x = fminf(fmaxf(acc[m][i],-30.f),30.f);
                bool th = (j>=120)&&(j<180);
                float e = __expf(th ? -2.f*x : -x);
                float numv = th ? (1.f-e) : 1.f;
                o[i] = f2b(numv/(1.f+e));
            }
            *(ushort4v*)&gact[nn][m*16 + jo] = o;
        }
        __syncthreads();
        // c2/h2 update (+lastT capture)
#pragma unroll
        for (int i=0;i<15;i++){
            int u = w*15 + i;
            float gi = b2f(gact[l][u]);
            float gf = b2f(gact[l][60+u]);
            float gg = b2f(gact[l][120+u]);
            float go = b2f(gact[l][180+u]);
            float c = gf*c2[i] + gi*gg;
            c2[i] = c;
            float h = go*tanhfast(c);
            hT2[u][l] = f2b(h);
            if (t == mylen-1) lastT[(size_t)u*Nc + n0 + l] = h;
        }
        __syncthreads();
    }
}

// Mean over P, concat [xw, path, yw] @ W^T + b, softmax. One block per batch row.
__global__ __launch_bounds__(320) void final_kernel(
    const float* __restrict__ lastT, const float* __restrict__ counts,
    const int* __restrict__ pair, const float* __restrict__ wemb,
    const float* __restrict__ W, const float* __restrict__ bvec,
    float* __restrict__ out)
{
    __shared__ float path[Hh];
    __shared__ float red[NRELc];
    const int b = blockIdx.x;
    const int tid = threadIdx.x;

    if (tid < Hh){
        float sum=0.f, cs=0.f;
        for (int p=0;p<Pc;p++){
            float cnt = counts[b*Pc+p];
            sum += lastT[(size_t)tid*Nc + b*Pc+p]*cnt;
            cs  += cnt;
        }
        path[tid] = sum/cs;
    }
    __syncthreads();

    const int rrel = tid>>6;
    const int lane = tid&63;
    const int xi = pair[b*2+0], yi = pair[b*2+1];
    const float* Wr = W + rrel*(2*ED+Hh);
    float acc=0.f;
    for (int d=lane; d<ED; d+=64) acc += wemb[xi*ED+d]*Wr[d];
    for (int k=lane; k<Hh; k+=64) acc += path[k]*Wr[ED+k];
    for (int d=lane; d<ED; d+=64) acc += wemb[yi*ED+d]*Wr[ED+Hh+d];
    for (int off=32; off>0; off>>=1) acc += __shfl_down(acc, off);
    if (lane==0) red[rrel] = acc + bvec[rrel];
    __syncthreads();

    if (tid==0){
        float m=red[0];
        for (int i=1;i<NRELc;i++) m=fmaxf(m,red[i]);
        float e[NRELc]; float sum=0.f;
        for (int i=0;i<NRELc;i++){ e[i]=__expf(red[i]-m); sum+=e[i]; }
        float inv=1.f/sum;
        for (int i=0;i<NRELc;i++) out[b*NRELc+i]=e[i]*inv;
    }
}

extern "C" void kernel_launch(void* const* d_in, const int* in_sizes, int n_in,
                              void* d_out, int out_size, void* d_ws, size_t ws_size,
                              hipStream_t stream)
{
    const int*   word_idx = (const int*)d_in[0];
    const int*   pos_idx  = (const int*)d_in[1];
    const int*   dep_idx  = (const int*)d_in[2];
    const int*   dir_idx  = (const int*)d_in[3];
    const int*   lengths  = (const int*)d_in[4];
    const float* counts   = (const float*)d_in[5];
    const int*   pair_idx = (const int*)d_in[6];
    const float* word_emb = (const float*)d_in[7];
    const float* pos_emb  = (const float*)d_in[8];
    const float* dep_emb  = (const float*)d_in[9];
    const float* dir_emb  = (const float*)d_in[10];
    const float* Wih0     = (const float*)d_in[11];
    const float* Whh0     = (const float*)d_in[12];
    const float* bih0     = (const float*)d_in[13];
    const float* bhh0     = (const float*)d_in[14];
    const float* Wih1     = (const float*)d_in[15];
    const float* Whh1     = (const float*)d_in[16];
    const float* bih1     = (const float*)d_in[17];
    const float* bhh1     = (const float*)d_in[18];
    const float* W        = (const float*)d_in[19];
    const float* bvec     = (const float*)d_in[20];
    float* out = (float*)d_out;

    // Workspace (~93 MB): fp32 region, then u16 region.
    float* p = (float*)d_ws;
    float* lastT = p; p += (size_t)Nc*Hh;
    u16* q = (u16*)p;
    u16* Aswz0 = q; q += 15*10*64*8;
    u16* A0F   = q; q += 15*2*64*8;
    u16* A1F   = q; q += 15*4*64*8;
    u16* tab   = q; q += (size_t)NTROWS*TROW;
    u16* ginF  = q; q += (size_t)NTILES*15*256;

    prep_kernel<<<256,256,0,stream>>>(Wih0,Whh0,Wih1,Whh1,bih0,bhh0,bih1,bhh1,
                                      pos_emb,dep_emb,dir_emb,
                                      Aswz0,A0F,A1F,tab);
    wxa_kernel<<<(VOC+127)/128,256,0,stream>>>(word_emb,Aswz0,tab);
    gadd_kernel<<<NTILES/4,256,0,stream>>>(word_idx,pos_idx,dep_idx,dir_idx,tab,ginF);
    recf_kernel<<<Nc/64,256,0,stream>>>(ginF,A0F,A1F,lengths,lastT);
    final_kernel<<<Bc,320,0,stream>>>(lastT,counts,pair_idx,word_emb,W,bvec,out);
}

// Round 6
// 305.191 us; speedup vs baseline: 2.8952x; 1.2943x over previous
//
#include <hip/hip_runtime.h>
#include <math.h>

#define ED 300
#define Hh 60
#define G4 240
#define NRELc 5
#define Bc 1024
#define Pc 16
#define Lc 8
#define Nc (Bc*Pc)        /* 16384 sequences */
#define VOC 50000
#define TROW 256          /* u16 per table row (512B) */
#define POS0 50000
#define DEP0 50050
#define DIR0 50100
#define NTROWS 50104

typedef __attribute__((ext_vector_type(8))) short short8v;
typedef __attribute__((ext_vector_type(4))) short short4v;
typedef __attribute__((ext_vector_type(4))) unsigned short ushort4v;
typedef __attribute__((ext_vector_type(4))) float f32x4;
typedef unsigned short u16;

__device__ __forceinline__ float sigf(float x){ return 1.f/(1.f+__expf(-x)); }
__device__ __forceinline__ float tanhfast(float x){
    x = fminf(fmaxf(x,-15.f),15.f);
    float e = __expf(-2.f*x);
    return (1.f-e)/(1.f+e);
}
__device__ __forceinline__ u16 f2b(float f){        // fp32 -> bf16 bits, RNE
    union{float f; unsigned u;} v; v.f=f;
    unsigned r = v.u + 0x7fffu + ((v.u>>16)&1u);
    return (u16)(r>>16);
}
__device__ __forceinline__ float b2f(u16 b){ return __uint_as_float(((unsigned)b)<<16); }
__device__ __forceinline__ float blo(unsigned d){ return __uint_as_float(d<<16); }
__device__ __forceinline__ float bhi(unsigned d){ return __uint_as_float(d & 0xffff0000u); }
// gate-interleaved permutation: permuted row j' = 4u+q  ->  original row q*60+u
__device__ __forceinline__ int origrow(int j){ return (j&3)*60 + (j>>2); }

// Build A-fragment-order weights (rows PERMUTED to gate-interleaved order).
// A-frag layout (R3-verified): lane l, elem e -> j = m*16+(l&15),
// k = ks*32 + 16*(e>>2) + 4*(l>>4) + (e&3).
__global__ __launch_bounds__(256) void prep_kernel(
    const float* __restrict__ Wih0, const float* __restrict__ Whh0,
    const float* __restrict__ Wih1, const float* __restrict__ Whh1,
    const float* __restrict__ bih0, const float* __restrict__ bhh0,
    const float* __restrict__ bih1, const float* __restrict__ bhh1,
    const float* __restrict__ pemb, const float* __restrict__ demb,
    const float* __restrict__ remb,
    u16* __restrict__ Aswz0, u16* __restrict__ A0P, u16* __restrict__ A1P,
    u16* __restrict__ tab)
{
    const int i0 = blockIdx.x*256 + threadIdx.x;
    const int stride = gridDim.x*256;
    // wxa A-frags: K=320 (310 real + bias@310), permuted rows
    for (int idx=i0; idx<15*10*64*8; idx+=stride){
        int e = idx&7, l = (idx>>3)&63, mk = idx>>9;
        int m = mk/10, ks = mk - m*10;
        int j = origrow(m*16 + (l&15));
        int k = ks*32 + ((e>>2)<<4) + ((l>>4)<<2) + (e&3);
        float v = 0.f;
        if (k < 310)      v = Wih0[j*310 + k];
        else if (k==310)  v = bih0[j] + bhh0[j];
        Aswz0[idx] = f2b(v);
    }
    // recurrence layer0 A: Whh0, K=64 (rows 60..63 zero), permuted rows
    for (int idx=i0; idx<15*2*64*8; idx+=stride){
        int e = idx&7, l = (idx>>3)&63, mk = idx>>9;
        int m = mk>>1, ks = mk&1;
        int j = origrow(m*16 + (l&15));
        int k = ks*32 + ((e>>2)<<4) + ((l>>4)<<2) + (e&3);
        A0P[idx] = f2b(k<60 ? Whh0[j*60+k] : 0.f);
    }
    // layer1 A: [Wih1 | bias@60 | 0 | Whh1@64..123 | 0], K=128, permuted rows
    for (int idx=i0; idx<15*4*64*8; idx+=stride){
        int e = idx&7, l = (idx>>3)&63, mk = idx>>9;
        int m = mk>>2, ks = mk&3;
        int j = origrow(m*16 + (l&15));
        int k = ks*32 + ((e>>2)<<4) + ((l>>4)<<2) + (e&3);
        float v = 0.f;
        if (k < 60)                  v = Wih1[j*60 + k];
        else if (k == 60)            v = bih1[j] + bhh1[j];
        else if (k >= 64 && k < 124) v = Whh1[j*60 + (k-64)];
        A1P[idx] = f2b(v);
    }
    // small tables (permuted j): pos / dep / dir(+bias0)
    for (int idx=i0; idx<50*240; idx+=stride){
        int p = idx/240, j = idx - p*240;
        int oj = origrow(j);
        float v = 0.f;
        for (int q=0;q<4;q++) v += Wih0[oj*310 + 300+q]*pemb[p*4+q];
        tab[(size_t)(POS0+p)*TROW + j] = f2b(v);
        float w = 0.f;
        for (int q=0;q<5;q++) w += Wih0[oj*310 + 304+q]*demb[p*5+q];
        tab[(size_t)(DEP0+p)*TROW + j] = f2b(w);
    }
    for (int idx=i0; idx<4*240; idx+=stride){
        int d = idx/240, j = idx - d*240;
        int oj = origrow(j);
        float v = remb[d]*Wih0[oj*310 + 309] + bih0[oj] + bhh0[oj];
        tab[(size_t)(DIR0+d)*TROW + j] = f2b(v);
    }
}

// Vocab precompute: tab[v][j] = sum_k Wih0[orig(j)][k]*wemb[v][k]  (j permuted via Aswz0)
__global__ __launch_bounds__(256,2) void wxa_kernel(
    const float* __restrict__ wemb, const u16* __restrict__ Aswz,
    u16* __restrict__ tab)
{
    const int tid = threadIdx.x;
    const int l  = tid & 63;
    const int wv = __builtin_amdgcn_readfirstlane(tid>>6);
    const int r0 = blockIdx.x*128;
    const int row0 = wv*32 + (l&15);
    const int v0 = r0 + row0, v1 = v0 + 16;
    const int v0c = v0 < VOC ? v0 : VOC-1;
    const int v1c = v1 < VOC ? v1 : VOC-1;
    const float* b0p = wemb + (size_t)v0c*300;
    const float* b1p = wemb + (size_t)v1c*300;

    f32x4 acc[15][2];
#pragma unroll
    for (int m=0;m<15;m++){
        acc[m][0] = f32x4{0.f,0.f,0.f,0.f};
        acc[m][1] = f32x4{0.f,0.f,0.f,0.f};
    }
    const float4 z4 = {0.f,0.f,0.f,0.f};
#pragma unroll
    for (int ks=0; ks<10; ++ks){
        const int k0 = ks*32 + ((l>>4)<<2);
        const int k1 = k0 + 16;
        float4 a0 = (k0<300) ? *(const float4*)(b0p+k0) : z4;
        float4 a1 = (k1<300) ? *(const float4*)(b0p+k1) : z4;
        float4 c0 = (k0<300) ? *(const float4*)(b1p+k0) : z4;
        float4 c1 = (k1<300) ? *(const float4*)(b1p+k1) : z4;
        short8v bf0 = {(short)f2b(a0.x),(short)f2b(a0.y),(short)f2b(a0.z),(short)f2b(a0.w),
                       (short)f2b(a1.x),(short)f2b(a1.y),(short)f2b(a1.z),(short)f2b(a1.w)};
        short8v bf1 = {(short)f2b(c0.x),(short)f2b(c0.y),(short)f2b(c0.z),(short)f2b(c0.w),
                       (short)f2b(c1.x),(short)f2b(c1.y),(short)f2b(c1.z),(short)f2b(c1.w)};
#pragma unroll
        for (int m=0;m<15;m++){
            short8v a = *(const short8v*)(Aswz + (size_t)(((m*10+ks)<<6) + l)*8);
            acc[m][0] = __builtin_amdgcn_mfma_f32_16x16x32_bf16(a, bf0, acc[m][0], 0,0,0);
            acc[m][1] = __builtin_amdgcn_mfma_f32_16x16x32_bf16(a, bf1, acc[m][1], 0,0,0);
        }
    }
#pragma unroll
    for (int m=0;m<15;m++){
        const int j = m*16 + ((l>>4)<<2);
        ushort4v s0, s1;
#pragma unroll
        for (int i=0;i<4;i++){ s0[i]=f2b(acc[m][0][i]); s1[i]=f2b(acc[m][1][i]); }
        if (v0 < VOC) *(ushort4v*)(tab + (size_t)v0*TROW + j) = s0;
        if (v1 < VOC) *(ushort4v*)(tab + (size_t)v1*TROW + j) = s1;
    }
}

// Fused gather + 2-layer LSTM recurrence. Block = 64 seqs, 4 waves, M-SPLIT:
// wave w owns m-tiles {4w..4w+3}∩[0,15) for ALL 64 seqs (4 n-tiles).
// Gate-interleaved rows: acc[m][i] = gate i of unit u=m*4+(l>>4), seq nt*16+(l&15).
__global__ __launch_bounds__(256,1) void recf_kernel(
    const int* __restrict__ widx, const int* __restrict__ pidx,
    const int* __restrict__ didx, const int* __restrict__ ridx,
    const u16* __restrict__ tab,
    const u16* __restrict__ A0P, const u16* __restrict__ A1P,
    const int* __restrict__ lens, float* __restrict__ lastT)
{
    __shared__ u16 ldsA0[15*2*64*8];                 // 30 KB
    __shared__ u16 ldsA1[15*4*64*8];                 // 60 KB
    __shared__ u16 hb1[64][68];                      // 8.5 KB, [seq][k], row60 = 1.0
    __shared__ u16 hb2[64][68];
    __shared__ __align__(16) unsigned offsL[8][64][4]; // 8 KB table byte-offsets

    const int tid = threadIdx.x;
    const int l   = tid & 63;
    const int w   = __builtin_amdgcn_readfirstlane(tid>>6);
    const int nn  = l & 15;
    const int gq  = l >> 4;
    const int jo  = gq << 2;
    const int n0  = blockIdx.x*64;

    // ---- stage A-fragments to LDS (coalesced uint4 copies)
    {
        const uint4* s0 = (const uint4*)A0P;
        const uint4* s1 = (const uint4*)A1P;
        uint4* d0 = (uint4*)ldsA0;
        uint4* d1 = (uint4*)ldsA1;
        for (int i=tid; i<15*2*64; i+=256) d0[i] = s0[i];
        for (int i=tid; i<15*4*64; i+=256) d1[i] = s1[i];
    }
    // ---- stage index offsets (coalesced: t fastest)
    for (int i=tid; i<512; i+=256){
        int t = i & 7, s = i >> 3;
        int n = n0 + s;
        offsL[t][s][0] = (unsigned)widx[n*Lc+t] << 9;
        offsL[t][s][1] = (unsigned)(POS0 + pidx[n*Lc+t]) << 9;
        offsL[t][s][2] = (unsigned)(DEP0 + didx[n*Lc+t]) << 9;
        offsL[t][s][3] = (unsigned)(DIR0 + ridx[n*Lc+t]) << 9;
    }
    // ---- init h/c state
    for (int i=tid; i<64*68; i+=256){ ((u16*)hb1)[i]=0; ((u16*)hb2)[i]=0; }
    __syncthreads();
    if (tid < 64) hb1[tid][60] = 0x3F80;   // bias feature = 1.0
    float c1[4][4], c2[4][4];
#pragma unroll
    for (int a=0;a<4;a++)
#pragma unroll
        for (int b=0;b<4;b++){ c1[a][b]=0.f; c2[a][b]=0.f; }
    int ln[4];
#pragma unroll
    for (int nt=0;nt<4;nt++) ln[nt] = lens[n0 + nt*16 + nn];
    __syncthreads();

    const char* tabb = (const char*)tab;

    for (int t=0;t<Lc;t++){
        f32x4 acc[4][4];
        // ---- gather gin = sum of 4 permuted table rows (fp32 sums)
        uint4 of[4];
#pragma unroll
        for (int nt=0;nt<4;nt++) of[nt] = *(const uint4*)&offsL[t][nt*16+nn][0];
#pragma unroll
        for (int ml=0;ml<4;ml++){
            const int m = w*4 + ml;
            if (m < 15){
                const int jb = (m*16 + jo)*2;
#pragma unroll
                for (int nt=0;nt<4;nt++){
                    uint2 ga = *(const uint2*)(tabb + of[nt].x + jb);
                    uint2 gb = *(const uint2*)(tabb + of[nt].y + jb);
                    uint2 gc = *(const uint2*)(tabb + of[nt].z + jb);
                    uint2 gd = *(const uint2*)(tabb + of[nt].w + jb);
                    f32x4 v;
                    v[0] = blo(ga.x)+blo(gb.x)+blo(gc.x)+blo(gd.x);
                    v[1] = bhi(ga.x)+bhi(gb.x)+bhi(gc.x)+bhi(gd.x);
                    v[2] = blo(ga.y)+blo(gb.y)+blo(gc.y)+blo(gd.y);
                    v[3] = bhi(ga.y)+bhi(gb.y)+bhi(gc.y)+bhi(gd.y);
                    acc[ml][nt] = v;
                }
            }
        }
        // ---- GEMM0: acc += Whh0 * h1(t-1)   (reads hb1(t-1))
#pragma unroll
        for (int ks=0;ks<2;ks++){
            short8v bfr[4];
#pragma unroll
            for (int nt=0;nt<4;nt++){
                const u16* row = &hb1[nt*16+nn][0];
                short4v lo = *(const short4v*)(row + ks*32 + jo);
                short4v hi = *(const short4v*)(row + ks*32 + jo + 16);
                bfr[nt] = short8v{lo[0],lo[1],lo[2],lo[3],hi[0],hi[1],hi[2],hi[3]};
            }
#pragma unroll
            for (int ml=0;ml<4;ml++){
                const int m = w*4 + ml;
                if (m < 15){
                    short8v a = *(const short8v*)(ldsA0 + (size_t)(((m*2+ks)<<6)+l)*8);
#pragma unroll
                    for (int nt=0;nt<4;nt++)
                        acc[ml][nt] = __builtin_amdgcn_mfma_f32_16x16x32_bf16(a, bfr[nt], acc[ml][nt], 0,0,0);
                }
            }
        }
        __syncthreads();     // all hb1(t-1) readers done
        // ---- act0 + c1/h1 update (all in-lane; gate-interleaved) -> write h1(t)
#pragma unroll
        for (int ml=0;ml<4;ml++){
            const int m = w*4 + ml;
            if (m < 15){
                const int u = m*4 + gq;
#pragma unroll
                for (int nt=0;nt<4;nt++){
                    float gi = sigf(acc[ml][nt][0]);
                    float gf = sigf(acc[ml][nt][1]);
                    float gg = tanhfast(acc[ml][nt][2]);
                    float go = sigf(acc[ml][nt][3]);
                    float cc = gf*c1[ml][nt] + gi*gg;
                    c1[ml][nt] = cc;
                    hb1[nt*16+nn][u] = f2b(go*tanhfast(cc));
                }
            }
        }
        __syncthreads();     // h1(t) complete
        // ---- GEMM1: gates1 = [Wih1|bias|Whh1] * [h1(t);1;0;h2(t-1);0]
#pragma unroll
        for (int ml=0;ml<4;ml++)
#pragma unroll
            for (int nt=0;nt<4;nt++) acc[ml][nt] = f32x4{0.f,0.f,0.f,0.f};
#pragma unroll
        for (int ks=0;ks<4;ks++){
            short8v bfr[4];
#pragma unroll
            for (int nt=0;nt<4;nt++){
                const u16* row = (ks<2) ? &hb1[nt*16+nn][0] : &hb2[nt*16+nn][0];
                const int kb = (ks&1)*32 + jo;
                short4v lo = *(const short4v*)(row + kb);
                short4v hi = *(const short4v*)(row + kb + 16);
                bfr[nt] = short8v{lo[0],lo[1],lo[2],lo[3],hi[0],hi[1],hi[2],hi[3]};
            }
#pragma unroll
            for (int ml=0;ml<4;ml++){
                const int m = w*4 + ml;
                if (m < 15){
                    short8v a = *(const short8v*)(ldsA1 + (size_t)(((m*4+ks)<<6)+l)*8);
#pragma unroll
                    for (int nt=0;nt<4;nt++)
                        acc[ml][nt] = __builtin_amdgcn_mfma_f32_16x16x32_bf16(a, bfr[nt], acc[ml][nt], 0,0,0);
                }
            }
        }
        __syncthreads();     // all hb2(t-1) readers done
        // ---- act1 + c2/h2 update -> write h2(t), capture lastT
#pragma unroll
        for (int ml=0;ml<4;ml++){
            const int m = w*4 + ml;
            if (m < 15){
                const int u = m*4 + gq;
#pragma unroll
                for (int nt=0;nt<4;nt++){
                    float gi = sigf(acc[ml][nt][0]);
                    float gf = sigf(acc[ml][nt][1]);
                    float gg = tanhfast(acc[ml][nt][2]);
                    float go = sigf(acc[ml][nt][3]);
                    float cc = gf*c2[ml][nt] + gi*gg;
                    c2[ml][nt] = cc;
                    float h = go*tanhfast(cc);
                    hb2[nt*16+nn][u] = f2b(h);
                    if (t == ln[nt]-1) lastT[(size_t)u*Nc + n0 + nt*16 + nn] = h;
                }
            }
        }
        // (no barrier needed here: next-t's first barrier orders hb2 writes
        //  before next GEMM1's reads; hb1 writes land after next-t barrier 1)
        __syncthreads();
    }
}

// Mean over P, concat [xw, path, yw] @ W^T + b, softmax. One block per batch row.
__global__ __launch_bounds__(320) void final_kernel(
    const float* __restrict__ lastT, const float* __restrict__ counts,
    const int* __restrict__ pair, const float* __restrict__ wemb,
    const float* __restrict__ W, const float* __restrict__ bvec,
    float* __restrict__ out)
{
    __shared__ float path[Hh];
    __shared__ float red[NRELc];
    const int b = blockIdx.x;
    const int tid = threadIdx.x;

    if (tid < Hh){
        float sum=0.f, cs=0.f;
        for (int p=0;p<Pc;p++){
            float cnt = counts[b*Pc+p];
            sum += lastT[(size_t)tid*Nc + b*Pc+p]*cnt;
            cs  += cnt;
        }
        path[tid] = sum/cs;
    }
    __syncthreads();

    const int rrel = tid>>6;
    const int lane = tid&63;
    const int xi = pair[b*2+0], yi = pair[b*2+1];
    const float* Wr = W + rrel*(2*ED+Hh);
    float acc=0.f;
    for (int d=lane; d<ED; d+=64) acc += wemb[xi*ED+d]*Wr[d];
    for (int k=lane; k<Hh; k+=64) acc += path[k]*Wr[ED+k];
    for (int d=lane; d<ED; d+=64) acc += wemb[yi*ED+d]*Wr[ED+Hh+d];
    for (int off=32; off>0; off>>=1) acc += __shfl_down(acc, off);
    if (lane==0) red[rrel] = acc + bvec[rrel];
    __syncthreads();

    if (tid==0){
        float m=red[0];
        for (int i=1;i<NRELc;i++) m=fmaxf(m,red[i]);
        float e[NRELc]; float sum=0.f;
        for (int i=0;i<NRELc;i++){ e[i]=__expf(red[i]-m); sum+=e[i]; }
        float inv=1.f/sum;
        for (int i=0;i<NRELc;i++) out[b*NRELc+i]=e[i]*inv;
    }
}

extern "C" void kernel_launch(void* const* d_in, const int* in_sizes, int n_in,
                              void* d_out, int out_size, void* d_ws, size_t ws_size,
                              hipStream_t stream)
{
    const int*   word_idx = (const int*)d_in[0];
    const int*   pos_idx  = (const int*)d_in[1];
    const int*   dep_idx  = (const int*)d_in[2];
    const int*   dir_idx  = (const int*)d_in[3];
    const int*   lengths  = (const int*)d_in[4];
    const float* counts   = (const float*)d_in[5];
    const int*   pair_idx = (const int*)d_in[6];
    const float* word_emb = (const float*)d_in[7];
    const float* pos_emb  = (const float*)d_in[8];
    const float* dep_emb  = (const float*)d_in[9];
    const float* dir_emb  = (const float*)d_in[10];
    const float* Wih0     = (const float*)d_in[11];
    const float* Whh0     = (const float*)d_in[12];
    const float* bih0     = (const float*)d_in[13];
    const float* bhh0     = (const float*)d_in[14];
    const float* Wih1     = (const float*)d_in[15];
    const float* Whh1     = (const float*)d_in[16];
    const float* bih1     = (const float*)d_in[17];
    const float* bhh1     = (const float*)d_in[18];
    const float* W        = (const float*)d_in[19];
    const float* bvec     = (const float*)d_in[20];
    float* out = (float*)d_out;

    // Workspace (~30 MB): fp32 region, then u16 region.
    float* p = (float*)d_ws;
    float* lastT = p; p += (size_t)Nc*Hh;
    u16* q = (u16*)p;
    u16* Aswz0 = q; q += 15*10*64*8;
    u16* A0P   = q; q += 15*2*64*8;
    u16* A1P   = q; q += 15*4*64*8;
    u16* tab   = q; q += (size_t)NTROWS*TROW;

    prep_kernel<<<256,256,0,stream>>>(Wih0,Whh0,Wih1,Whh1,bih0,bhh0,bih1,bhh1,
                                      pos_emb,dep_emb,dir_emb,
                                      Aswz0,A0P,A1P,tab);
    wxa_kernel<<<(VOC+127)/128,256,0,stream>>>(word_emb,Aswz0,tab);
    recf_kernel<<<Nc/64,256,0,stream>>>(word_idx,pos_idx,dep_idx,dir_idx,
                                        tab,A0P,A1P,lengths,lastT);
    final_kernel<<<Bc,320,0,stream>>>(lastT,counts,pair_idx,word_emb,W,bvec,out);
}

// Round 7
// 293.160 us; speedup vs baseline: 3.0140x; 1.0410x over previous
//
#include <hip/hip_runtime.h>
#include <math.h>

#define ED 300
#define Hh 60
#define G4 240
#define NRELc 5
#define Bc 1024
#define Pc 16
#define Lc 8
#define Nc (Bc*Pc)        /* 16384 sequences */
#define VOC 50000
#define TROW 256          /* u16 per table row (512B) */
#define POS0 50000
#define DEP0 50050
#define DIR0 50100
#define NTROWS 50104
#define NTILES 8192       /* Rc/16 = Lc*Nc/16 */

typedef __attribute__((ext_vector_type(8))) short short8v;
typedef __attribute__((ext_vector_type(4))) short short4v;
typedef __attribute__((ext_vector_type(4))) unsigned short ushort4v;
typedef __attribute__((ext_vector_type(4))) float f32x4;
typedef unsigned short u16;

__device__ __forceinline__ float sigf(float x){ return 1.f/(1.f+__expf(-x)); }
__device__ __forceinline__ float tanhfast(float x){
    x = fminf(fmaxf(x,-15.f),15.f);
    float e = __expf(-2.f*x);
    return (1.f-e)/(1.f+e);
}
__device__ __forceinline__ u16 f2b(float f){        // fp32 -> bf16 bits, RNE
    union{float f; unsigned u;} v; v.f=f;
    unsigned r = v.u + 0x7fffu + ((v.u>>16)&1u);
    return (u16)(r>>16);
}
__device__ __forceinline__ float b2f(u16 b){ return __uint_as_float(((unsigned)b)<<16); }
__device__ __forceinline__ float blo(unsigned d){ return __uint_as_float(d<<16); }
__device__ __forceinline__ float bhi(unsigned d){ return __uint_as_float(d & 0xffff0000u); }
// gate-interleaved permutation: permuted row j' = 4u+q  ->  original row q*60+u
__device__ __forceinline__ int origrow(int j){ return (j&3)*60 + (j>>2); }

// Build A-fragment-order weights (rows PERMUTED to gate-interleaved order).
// A-frag layout (R3-verified): lane l, elem e -> j = m*16+(l&15),
// k = ks*32 + 16*(e>>2) + 4*(l>>4) + (e&3).
__global__ __launch_bounds__(256) void prep_kernel(
    const float* __restrict__ Wih0, const float* __restrict__ Whh0,
    const float* __restrict__ Wih1, const float* __restrict__ Whh1,
    const float* __restrict__ bih0, const float* __restrict__ bhh0,
    const float* __restrict__ bih1, const float* __restrict__ bhh1,
    const float* __restrict__ pemb, const float* __restrict__ demb,
    const float* __restrict__ remb,
    u16* __restrict__ Aswz0, u16* __restrict__ A0P, u16* __restrict__ A1P,
    u16* __restrict__ tab)
{
    const int i0 = blockIdx.x*256 + threadIdx.x;
    const int stride = gridDim.x*256;
    // wxa A-frags: K=320 (310 real + bias@310), permuted rows
    for (int idx=i0; idx<15*10*64*8; idx+=stride){
        int e = idx&7, l = (idx>>3)&63, mk = idx>>9;
        int m = mk/10, ks = mk - m*10;
        int j = origrow(m*16 + (l&15));
        int k = ks*32 + ((e>>2)<<4) + ((l>>4)<<2) + (e&3);
        float v = 0.f;
        if (k < 310)      v = Wih0[j*310 + k];
        else if (k==310)  v = bih0[j] + bhh0[j];
        Aswz0[idx] = f2b(v);
    }
    // recurrence layer0 A: Whh0, K=64 (rows 60..63 zero), permuted rows
    for (int idx=i0; idx<15*2*64*8; idx+=stride){
        int e = idx&7, l = (idx>>3)&63, mk = idx>>9;
        int m = mk>>1, ks = mk&1;
        int j = origrow(m*16 + (l&15));
        int k = ks*32 + ((e>>2)<<4) + ((l>>4)<<2) + (e&3);
        A0P[idx] = f2b(k<60 ? Whh0[j*60+k] : 0.f);
    }
    // layer1 A: [Wih1 | bias@60 | 0 | Whh1@64..123 | 0], K=128, permuted rows
    for (int idx=i0; idx<15*4*64*8; idx+=stride){
        int e = idx&7, l = (idx>>3)&63, mk = idx>>9;
        int m = mk>>2, ks = mk&3;
        int j = origrow(m*16 + (l&15));
        int k = ks*32 + ((e>>2)<<4) + ((l>>4)<<2) + (e&3);
        float v = 0.f;
        if (k < 60)                  v = Wih1[j*60 + k];
        else if (k == 60)            v = bih1[j] + bhh1[j];
        else if (k >= 64 && k < 124) v = Whh1[j*60 + (k-64)];
        A1P[idx] = f2b(v);
    }
    // small tables (permuted j): pos / dep / dir(+bias0)
    for (int idx=i0; idx<50*240; idx+=stride){
        int p = idx/240, j = idx - p*240;
        int oj = origrow(j);
        float v = 0.f;
        for (int q=0;q<4;q++) v += Wih0[oj*310 + 300+q]*pemb[p*4+q];
        tab[(size_t)(POS0+p)*TROW + j] = f2b(v);
        float w = 0.f;
        for (int q=0;q<5;q++) w += Wih0[oj*310 + 304+q]*demb[p*5+q];
        tab[(size_t)(DEP0+p)*TROW + j] = f2b(w);
    }
    for (int idx=i0; idx<4*240; idx+=stride){
        int d = idx/240, j = idx - d*240;
        int oj = origrow(j);
        float v = remb[d]*Wih0[oj*310 + 309] + bih0[oj] + bhh0[oj];
        tab[(size_t)(DIR0+d)*TROW + j] = f2b(v);
    }
}

// Vocab precompute: tab[v][j] = sum_k Wih0[orig(j)][k]*wemb[v][k]  (j permuted via Aswz0)
__global__ __launch_bounds__(256,2) void wxa_kernel(
    const float* __restrict__ wemb, const u16* __restrict__ Aswz,
    u16* __restrict__ tab)
{
    const int tid = threadIdx.x;
    const int l  = tid & 63;
    const int wv = __builtin_amdgcn_readfirstlane(tid>>6);
    const int r0 = blockIdx.x*128;
    const int row0 = wv*32 + (l&15);
    const int v0 = r0 + row0, v1 = v0 + 16;
    const int v0c = v0 < VOC ? v0 : VOC-1;
    const int v1c = v1 < VOC ? v1 : VOC-1;
    const float* b0p = wemb + (size_t)v0c*300;
    const float* b1p = wemb + (size_t)v1c*300;

    f32x4 acc[15][2];
#pragma unroll
    for (int m=0;m<15;m++){
        acc[m][0] = f32x4{0.f,0.f,0.f,0.f};
        acc[m][1] = f32x4{0.f,0.f,0.f,0.f};
    }
    const float4 z4 = {0.f,0.f,0.f,0.f};
#pragma unroll
    for (int ks=0; ks<10; ++ks){
        const int k0 = ks*32 + ((l>>4)<<2);
        const int k1 = k0 + 16;
        float4 a0 = (k0<300) ? *(const float4*)(b0p+k0) : z4;
        float4 a1 = (k1<300) ? *(const float4*)(b0p+k1) : z4;
        float4 c0 = (k0<300) ? *(const float4*)(b1p+k0) : z4;
        float4 c1 = (k1<300) ? *(const float4*)(b1p+k1) : z4;
        short8v bf0 = {(short)f2b(a0.x),(short)f2b(a0.y),(short)f2b(a0.z),(short)f2b(a0.w),
                       (short)f2b(a1.x),(short)f2b(a1.y),(short)f2b(a1.z),(short)f2b(a1.w)};
        short8v bf1 = {(short)f2b(c0.x),(short)f2b(c0.y),(short)f2b(c0.z),(short)f2b(c0.w),
                       (short)f2b(c1.x),(short)f2b(c1.y),(short)f2b(c1.z),(short)f2b(c1.w)};
#pragma unroll
        for (int m=0;m<15;m++){
            short8v a = *(const short8v*)(Aswz + (size_t)(((m*10+ks)<<6) + l)*8);
            acc[m][0] = __builtin_amdgcn_mfma_f32_16x16x32_bf16(a, bf0, acc[m][0], 0,0,0);
            acc[m][1] = __builtin_amdgcn_mfma_f32_16x16x32_bf16(a, bf1, acc[m][1], 0,0,0);
        }
    }
#pragma unroll
    for (int m=0;m<15;m++){
        const int j = m*16 + ((l>>4)<<2);
        ushort4v s0, s1;
#pragma unroll
        for (int i=0;i<4;i++){ s0[i]=f2b(acc[m][0][i]); s1[i]=f2b(acc[m][1][i]); }
        if (v0 < VOC) *(ushort4v*)(tab + (size_t)v0*TROW + j) = s0;
        if (v1 < VOC) *(ushort4v*)(tab + (size_t)v1*TROW + j) = s1;
    }
}

// gin0 in C-FRAG order: ginF[(s*15+m)*256 + l*4 + i] = gin0[j][r],
// j = m*16+4*(l>>4)+i (permuted), r = s*16+(l&15), s = t*1024 + tile.
__global__ __launch_bounds__(256,4) void gadd_kernel(
    const int* __restrict__ widx, const int* __restrict__ pidx,
    const int* __restrict__ didx, const int* __restrict__ ridx,
    const u16* __restrict__ tab, u16* __restrict__ ginF)
{
    const int tid = threadIdx.x;
    const int l  = tid & 63;
    const int wv = tid >> 6;
    const int s  = blockIdx.x*4 + wv;      // 0..8191
    const int t  = s >> 10;
    const int n  = ((s & 1023)<<4) + (l&15);
    const int w  = widx[n*Lc+t];
    const int p  = pidx[n*Lc+t];
    const int d  = didx[n*Lc+t];
    const int dd = ridx[n*Lc+t];
    const u16* rw = tab + (size_t)w*TROW;
    const u16* rp = tab + (size_t)(POS0+p)*TROW;
    const u16* rd = tab + (size_t)(DEP0+d)*TROW;
    const u16* rr = tab + (size_t)(DIR0+dd)*TROW;
    const int j0 = (l>>4)<<2;

#pragma unroll
    for (int m=0;m<15;m++){
        const int j = m*16 + j0;
        uint2 aw = *(const uint2*)(rw + j);
        uint2 ap = *(const uint2*)(rp + j);
        uint2 ad = *(const uint2*)(rd + j);
        uint2 ar = *(const uint2*)(rr + j);
        ushort4v o;
        o[0] = f2b(blo(aw.x)+blo(ap.x)+blo(ad.x)+blo(ar.x));
        o[1] = f2b(bhi(aw.x)+bhi(ap.x)+bhi(ad.x)+bhi(ar.x));
        o[2] = f2b(blo(aw.y)+blo(ap.y)+blo(ad.y)+blo(ar.y));
        o[3] = f2b(bhi(aw.y)+bhi(ap.y)+bhi(ad.y)+bhi(ar.y));
        *(ushort4v*)(ginF + (((size_t)s*15+m)<<8) + (l<<2)) = o;
    }
}

// Fused 2-layer LSTM recurrence via MFMA. Block = 64 seqs, 768 thr = 12 waves:
// wave (mg = w>>2, nt = w&3): mg owns m-tiles mg*5..mg*5+4 (15 exactly), nt = 16-seq tile.
// Gate-interleaved rows: acc[ml][i] = gate i of unit u=m*4+(l>>4), seq nt*16+(l&15).
__global__ __launch_bounds__(768,3) void recf_kernel(
    const u16* __restrict__ ginF,
    const u16* __restrict__ A0P, const u16* __restrict__ A1P,
    const int* __restrict__ lens, float* __restrict__ lastT)
{
    __shared__ u16 ldsA1[15*4*64*8];   // 60 KB
    __shared__ u16 hb1[64][68];        // [seq][k] bf16, row k=60 is bias 1.0
    __shared__ u16 hb2[64][68];

    const int tid = threadIdx.x;
    const int l   = tid & 63;
    const int w   = __builtin_amdgcn_readfirstlane(tid>>6);   // 0..11
    const int mg  = w >> 2;           // 0..2
    const int nt  = w & 3;            // 0..3
    const int nn  = l & 15;
    const int gq  = l >> 4;
    const int jo  = gq << 2;
    const int n0  = blockIdx.x*64;
    const int seq = nt*16 + nn;       // within block

    // stage A1 to LDS (once per CU)
    {
        const uint4* s1 = (const uint4*)A1P;
        uint4* d1 = (uint4*)ldsA1;
        for (int i=tid; i<15*4*64; i+=768) d1[i] = s1[i];
    }
    // A0 frags in registers: 5 m-tiles x 2 ks
    short8v a0r[5][2];
#pragma unroll
    for (int ml=0; ml<5; ml++){
        const int m = mg*5 + ml;
#pragma unroll
        for (int ks=0; ks<2; ks++)
            a0r[ml][ks] = *(const short8v*)(A0P + (size_t)(((m*2+ks)<<6)+l)*8);
    }
    for (int i=tid; i<64*68; i+=768){ ((u16*)hb1)[i]=0; ((u16*)hb2)[i]=0; }
    __syncthreads();
    if (tid < 64) hb1[tid][60] = 0x3F80;   // bias feature = 1.0
    float c1[5], c2[5];
#pragma unroll
    for (int i=0;i<5;i++){ c1[i]=0.f; c2[i]=0.f; }
    const int ln = lens[n0 + seq];
    __syncthreads();

    for (int t=0;t<Lc;t++){
        const size_t s = (size_t)t*1024 + blockIdx.x*4 + nt;
        f32x4 acc[5];
        // acc init from ginF (coalesced streaming 8B/lane)
#pragma unroll
        for (int ml=0;ml<5;ml++){
            const int m = mg*5 + ml;
            ushort4v g4 = *(const ushort4v*)(ginF + (((size_t)s*15+m)<<8) + (l<<2));
            acc[ml] = f32x4{ b2f(g4[0]), b2f(g4[1]), b2f(g4[2]), b2f(g4[3]) };
        }
        // GEMM0: acc += Whh0 * h1(t-1)
#pragma unroll
        for (int ks=0;ks<2;ks++){
            const u16* row = &hb1[seq][0];
            short4v lo = *(const short4v*)(row + ks*32 + jo);
            short4v hi = *(const short4v*)(row + ks*32 + jo + 16);
            short8v b = {lo[0],lo[1],lo[2],lo[3],hi[0],hi[1],hi[2],hi[3]};
#pragma unroll
            for (int ml=0;ml<5;ml++)
                acc[ml] = __builtin_amdgcn_mfma_f32_16x16x32_bf16(a0r[ml][ks], b, acc[ml], 0,0,0);
        }
        __syncthreads();    // B1: all GEMM0 reads of hb1(t-1) done
        // act0 + c1/h1 update -> hb1(t)
#pragma unroll
        for (int ml=0;ml<5;ml++){
            const int u = (mg*5+ml)*4 + gq;
            float gi = sigf(acc[ml][0]);
            float gf = sigf(acc[ml][1]);
            float gg = tanhfast(acc[ml][2]);
            float go = sigf(acc[ml][3]);
            float cc = gf*c1[ml] + gi*gg;
            c1[ml] = cc;
            hb1[seq][u] = f2b(go*tanhfast(cc));
        }
        __syncthreads();    // B2: h1(t) complete
        // GEMM1: gates1 = [Wih1|bias|Whh1] * [h1(t);1;0;h2(t-1);0]
#pragma unroll
        for (int ml=0;ml<5;ml++) acc[ml] = f32x4{0.f,0.f,0.f,0.f};
#pragma unroll
        for (int ks=0;ks<4;ks++){
            const u16* row = (ks<2) ? &hb1[seq][0] : &hb2[seq][0];
            const int kb = (ks&1)*32 + jo;
            short4v lo = *(const short4v*)(row + kb);
            short4v hi = *(const short4v*)(row + kb + 16);
            short8v b = {lo[0],lo[1],lo[2],lo[3],hi[0],hi[1],hi[2],hi[3]};
#pragma unroll
            for (int ml=0;ml<5;ml++){
                const int m = mg*5 + ml;
                short8v a = *(const short8v*)(ldsA1 + (size_t)(((m*4+ks)<<6)+l)*8);
                acc[ml] = __builtin_amdgcn_mfma_f32_16x16x32_bf16(a, b, acc[ml], 0,0,0);
            }
        }
        __syncthreads();    // B3: all GEMM1 reads of hb2(t-1) done
        // act1 + c2/h2 update -> hb2(t), capture lastT
#pragma unroll
        for (int ml=0;ml<5;ml++){
            const int u = (mg*5+ml)*4 + gq;
            float gi = sigf(acc[ml][0]);
            float gf = sigf(acc[ml][1]);
            float gg = tanhfast(acc[ml][2]);
            float go = sigf(acc[ml][3]);
            float cc = gf*c2[ml] + gi*gg;
            c2[ml] = cc;
            float h = go*tanhfast(cc);
            hb2[seq][u] = f2b(h);
            if (t == ln-1) lastT[(size_t)(n0+seq)*64 + u] = h;
        }
        // no barrier here: hb2(t) writes are ordered before GEMM1(t+1) reads by
        // B1(t+1)+B2(t+1); hb1(t+1) writes wait on B1(t+1) after GEMM1(t) reads.
    }
}

// Mean over P, concat [xw, path, yw] @ W^T + b, softmax. One block per batch row.
__global__ __launch_bounds__(320) void final_kernel(
    const float* __restrict__ lastT, const float* __restrict__ counts,
    const int* __restrict__ pair, const float* __restrict__ wemb,
    const float* __restrict__ W, const float* __restrict__ bvec,
    float* __restrict__ out)
{
    __shared__ float path[Hh];
    __shared__ float red[NRELc];
    const int b = blockIdx.x;
    const int tid = threadIdx.x;

    if (tid < Hh){
        float sum=0.f, cs=0.f;
        for (int p=0;p<Pc;p++){
            float cnt = counts[b*Pc+p];
            sum += lastT[(size_t)(b*Pc+p)*64 + tid]*cnt;
            cs  += cnt;
        }
        path[tid] = sum/cs;
    }
    __syncthreads();

    const int rrel = tid>>6;
    const int lane = tid&63;
    const int xi = pair[b*2+0], yi = pair[b*2+1];
    const float* Wr = W + rrel*(2*ED+Hh);
    float acc=0.f;
    for (int d=lane; d<ED; d+=64) acc += wemb[xi*ED+d]*Wr[d];
    for (int k=lane; k<Hh; k+=64) acc += path[k]*Wr[ED+k];
    for (int d=lane; d<ED; d+=64) acc += wemb[yi*ED+d]*Wr[ED+Hh+d];
    for (int off=32; off>0; off>>=1) acc += __shfl_down(acc, off);
    if (lane==0) red[rrel] = acc + bvec[rrel];
    __syncthreads();

    if (tid==0){
        float m=red[0];
        for (int i=1;i<NRELc;i++) m=fmaxf(m,red[i]);
        float e[NRELc]; float sum=0.f;
        for (int i=0;i<NRELc;i++){ e[i]=__expf(red[i]-m); sum+=e[i]; }
        float inv=1.f/sum;
        for (int i=0;i<NRELc;i++) out[b*NRELc+i]=e[i]*inv;
    }
}

extern "C" void kernel_launch(void* const* d_in, const int* in_sizes, int n_in,
                              void* d_out, int out_size, void* d_ws, size_t ws_size,
                              hipStream_t stream)
{
    const int*   word_idx = (const int*)d_in[0];
    const int*   pos_idx  = (const int*)d_in[1];
    const int*   dep_idx  = (const int*)d_in[2];
    const int*   dir_idx  = (const int*)d_in[3];
    const int*   lengths  = (const int*)d_in[4];
    const float* counts   = (const float*)d_in[5];
    const int*   pair_idx = (const int*)d_in[6];
    const float* word_emb = (const float*)d_in[7];
    const float* pos_emb  = (const float*)d_in[8];
    const float* dep_emb  = (const float*)d_in[9];
    const float* dir_emb  = (const float*)d_in[10];
    const float* Wih0     = (const float*)d_in[11];
    const float* Whh0     = (const float*)d_in[12];
    const float* bih0     = (const float*)d_in[13];
    const float* bhh0     = (const float*)d_in[14];
    const float* Wih1     = (const float*)d_in[15];
    const float* Whh1     = (const float*)d_in[16];
    const float* bih1     = (const float*)d_in[17];
    const float* bhh1     = (const float*)d_in[18];
    const float* W        = (const float*)d_in[19];
    const float* bvec     = (const float*)d_in[20];
    float* out = (float*)d_out;

    // Workspace (~95 MB): fp32 region, then u16 region.
    float* p = (float*)d_ws;
    float* lastT = p; p += (size_t)Nc*64;
    u16* q = (u16*)p;
    u16* Aswz0 = q; q += 15*10*64*8;
    u16* A0P   = q; q += 15*2*64*8;
    u16* A1P   = q; q += 15*4*64*8;
    u16* tab   = q; q += (size_t)NTROWS*TROW;
    u16* ginF  = q; q += (size_t)NTILES*15*256;

    prep_kernel<<<256,256,0,stream>>>(Wih0,Whh0,Wih1,Whh1,bih0,bhh0,bih1,bhh1,
                                      pos_emb,dep_emb,dir_emb,
                                      Aswz0,A0P,A1P,tab);
    wxa_kernel<<<(VOC+127)/128,256,0,stream>>>(word_emb,Aswz0,tab);
    gadd_kernel<<<NTILES/4,256,0,stream>>>(word_idx,pos_idx,dep_idx,dir_idx,tab,ginF);
    recf_kernel<<<Nc/64,768,0,stream>>>(ginF,A0P,A1P,lengths,lastT);
    final_kernel<<<Bc,320,0,stream>>>(lastT,counts,pair_idx,word_emb,W,bvec,out);
}